// Round 16
// baseline (581.582 us; speedup 1.0000x reference)
//
#include <hip/hip_runtime.h>

#define N_DIM 4096
#define C_DIM 512
#define CN_ ((long)C_DIM * (long)N_DIM)   // 2,097,152

typedef unsigned short ushort_t;
typedef __attribute__((ext_vector_type(8))) short bf16x8;
typedef __attribute__((ext_vector_type(4))) float f32x4;

typedef const __attribute__((address_space(1))) unsigned int* gas_t;
typedef __attribute__((address_space(3))) unsigned int* las_t;
#define GLOAD(g, l) __builtin_amdgcn_global_load_lds((gas_t)(g), (las_t)(l), 16, 0, 0)

__device__ __forceinline__ ushort_t f2b(float f) {
    unsigned u = __builtin_bit_cast(unsigned, f);
    u += 0x7fffu + ((u >> 16) & 1u);
    return (ushort_t)(u >> 16);
}
__device__ __forceinline__ float b2f(ushort_t s) {
    return __builtin_bit_cast(float, (unsigned)s << 16);
}

enum { EPI_NONE = 0, EPI_PHI = 1, EPI_RELU_BIAS = 2, EPI_RES_BIAS = 3, EPI_PRE = 4 };

// raw barrier + scheduler fences (rule #18 / m152 discipline)
#define SBAR { __builtin_amdgcn_sched_barrier(0); __builtin_amdgcn_s_barrier(); __builtin_amdgcn_sched_barrier(0); }
#define WAITV0 { asm volatile("s_waitcnt vmcnt(0)" ::: "memory"); __builtin_amdgcn_sched_barrier(0); }
#define WAITV4 { asm volatile("s_waitcnt vmcnt(4)" ::: "memory"); __builtin_amdgcn_sched_barrier(0); }
#define WAITV8 { asm volatile("s_waitcnt vmcnt(8)" ::: "memory"); __builtin_amdgcn_sched_barrier(0); }

// Shared K-loop: 128x128 tile, 4 waves, BK=32, two LDS stage buffers.
// Counted vmcnt: next tile's loads stay in flight across barriers (T4).
// T5: setprio(1) around MFMA cluster.
#define STAGE(q, koff) { \
    GLOAD(ap0 + (koff), &Als[q][la0]); \
    GLOAD(ap1 + (koff), &Als[q][la1]); \
    GLOAD(bp0 + (koff), &Bls[q][la0]); \
    GLOAD(bp1 + (koff), &Bls[q][la1]); }

#define COMPUTE(q) { \
    bf16x8 af[4], bfv[4]; \
    _Pragma("unroll") for (int m_ = 0; m_ < 4; ++m_) \
        af[m_] = *(const bf16x8*)&Als[q][(wr + m_ * 16 + fr) * 32 + rsw]; \
    _Pragma("unroll") for (int nf_ = 0; nf_ < 4; ++nf_) \
        bfv[nf_] = *(const bf16x8*)&Bls[q][(wc + nf_ * 16 + fr) * 32 + rsw]; \
    __builtin_amdgcn_s_setprio(1); \
    _Pragma("unroll") for (int m_ = 0; m_ < 4; ++m_) \
        _Pragma("unroll") for (int nf_ = 0; nf_ < 4; ++nf_) \
            acc[m_][nf_] = __builtin_amdgcn_mfma_f32_16x16x32_bf16( \
                af[m_], bfv[nf_], acc[m_][nf_], 0, 0, 0); \
    __builtin_amdgcn_s_setprio(0); }

#define KLOOP(K_) { \
    const int S_ = (K_) / 32; \
    STAGE(0, 0); \
    if (S_ > 1) STAGE(1, 32); \
    int s_ = 0; \
    while (true) { \
        if (s_ + 1 < S_) { WAITV4 } else { WAITV0 } \
        SBAR; \
        COMPUTE(s_ & 1); \
        SBAR; \
        if (s_ + 2 < S_) STAGE(s_ & 1, (s_ + 2) * 32); \
        ++s_; \
        if (s_ >= S_) break; \
    } }

// ---------------------------------------------------------------------------
// bf16 MFMA GEMM: OUT[z][n][o] = epi( sum_k A[z][n][k] * W[o][k] )
// DEN: den[z][n] += sum_o v * ksum[(z&3)][o]  (ksum in bias, den in auxf)
// QGS: qg[z][o] += sum_n v  (qg in auxf; pre-zeroed)
// ---------------------------------------------------------------------------
template<int EPI, bool GROUPED, bool OBF, bool DEN, bool QGS>
__global__ __launch_bounds__(256, 3) void mfma_gemm(
    const ushort_t* __restrict__ Wb, const ushort_t* __restrict__ A,
    void* __restrict__ OUTV, const float* __restrict__ bias,
    const ushort_t* __restrict__ auxb, const float* __restrict__ auxf,
    int K, int O, int a_rstride, long a_zstride, long o_zstride, long auxb_zstride,
    int xt, int yt)
{
    __shared__ ushort_t Als[2][128 * 32];
    __shared__ ushort_t Bls[2][128 * 32];
    const int tid = threadIdx.x;

    const int L = blockIdx.x;
    const int gpx = (gridDim.x >> 3) / xt;
    const int xcd = L & 7;
    const int j = L >> 3;
    const int xtile = j % xt;
    const int g = xcd * gpx + j / xt;
    const int ytile = g % yt;
    const int z = g / yt;

    const int o0 = xtile * 128;
    const int n0 = ytile * 128;
    const ushort_t* Az = A + (long)z * a_zstride;
    const ushort_t* Wp = Wb;
    int kbase = 0, obase = o0;
    if (GROUPED) { int gg = o0 >> 7; Wp = Wb + (long)gg * (128 * 128); kbase = gg << 7; obase = 0; }

    const int w = tid >> 6, l = tid & 63;
    const int lr = l >> 2, lg = l & 3;
    const int rA0 = w * 32 + lr, rA1 = w * 32 + 16 + lr;
    const int gA0 = lg ^ ((rA0 >> 1) & 3), gA1 = lg ^ ((rA1 >> 1) & 3);
    const ushort_t* ap0 = Az + (long)(n0 + rA0) * a_rstride + kbase + gA0 * 8;
    const ushort_t* ap1 = Az + (long)(n0 + rA1) * a_rstride + kbase + gA1 * 8;
    const ushort_t* bp0 = Wp + (long)(obase + rA0) * K + gA0 * 8;
    const ushort_t* bp1 = Wp + (long)(obase + rA1) * K + gA1 * 8;
    const int la0 = (w * 32) * 32, la1 = (w * 32 + 16) * 32;

    const int wr = (w >> 1) * 64, wc = (w & 1) * 64;
    const int fr = l & 15, ks = l >> 4;
    const int rsw = (ks ^ ((fr >> 1) & 3)) << 3;

    f32x4 acc[4][4];
#pragma unroll
    for (int m = 0; m < 4; ++m)
#pragma unroll
        for (int nf = 0; nf < 4; ++nf) acc[m][nf] = f32x4{0.f, 0.f, 0.f, 0.f};

    KLOOP(K);

    float dsum[4][4];
    if (DEN) {
#pragma unroll
        for (int m = 0; m < 4; ++m)
#pragma unroll
            for (int j2 = 0; j2 < 4; ++j2) dsum[m][j2] = 0.f;
    }
    float qsum[4];
    if (QGS) {
#pragma unroll
        for (int nf = 0; nf < 4; ++nf) qsum[nf] = 0.f;
    }

#pragma unroll
    for (int m = 0; m < 4; ++m) {
#pragma unroll
        for (int nf = 0; nf < 4; ++nf) {
            const int oo = o0 + wc + nf * 16 + fr;
            float bval = 0.f;
            if (EPI == EPI_RELU_BIAS || EPI == EPI_RES_BIAS) bval = bias[oo];
            float kw = 0.f;
            if (DEN) kw = bias[((z & 3) << 9) + oo];
#pragma unroll
            for (int j2 = 0; j2 < 4; ++j2) {
                const int nn = n0 + wr + m * 16 + ks * 4 + j2;
                const long ridx = (long)nn * O + oo;
                float v = acc[m][nf][j2];
                if (EPI == EPI_PHI)            v = fmaxf(v, 0.f) + 1.f;
                else if (EPI == EPI_RELU_BIAS) v = fmaxf(v + bval, 0.f);
                else if (EPI == EPI_RES_BIAS)  v = v + bval + b2f(auxb[(long)z * auxb_zstride + ridx]);
                else if (EPI == EPI_PRE)       v = b2f(auxb[(long)z * auxb_zstride + ridx]) + auxf[ridx] * v;
                if (DEN) dsum[m][j2] += v * kw;
                if (QGS) qsum[nf] += v;
                if (OBF) ((ushort_t*)OUTV)[(long)z * o_zstride + ridx] = f2b(v);
                else     ((float*)OUTV)[(long)z * o_zstride + ridx] = v;
            }
        }
    }

    if (DEN) {
#pragma unroll
        for (int m = 0; m < 4; ++m)
#pragma unroll
            for (int j2 = 0; j2 < 4; ++j2) {
                float d = dsum[m][j2];
                d += __shfl_xor(d, 1); d += __shfl_xor(d, 2);
                d += __shfl_xor(d, 4); d += __shfl_xor(d, 8);
                if (fr == 0) {
                    const int nn = n0 + wr + m * 16 + ks * 4 + j2;
                    atomicAdd((float*)&auxf[(long)z * N_DIM + nn], d);
                }
            }
    }
    if (QGS) {
#pragma unroll
        for (int nf = 0; nf < 4; ++nf) {
            float d = qsum[nf];
            d += __shfl_xor(d, 16);
            d += __shfl_xor(d, 32);
            if (ks == 0) {
                const int oo = o0 + wc + nf * 16 + fr;
                atomicAdd((float*)&auxf[((long)z << 9) + oo], d);
            }
        }
    }
}

// ---------------------------------------------------------------------------
// kv: kvp[nch][b][d][c] = sum_{n in 512-chunk nch} v0c[b][d][n] * khat[b][c][n]
// ---------------------------------------------------------------------------
__global__ __launch_bounds__(256, 3) void kv_mfma(
    const ushort_t* __restrict__ v0c, const ushort_t* __restrict__ khat,
    float* __restrict__ kvp)
{
    __shared__ ushort_t Als[2][128 * 32];
    __shared__ ushort_t Bls[2][128 * 32];
    const int tid = threadIdx.x;
    const int L = blockIdx.x;
    const int gpx = (gridDim.x >> 3) >> 2;
    const int xcd = L & 7;
    const int j = L >> 3;
    const int xtile = j & 3;
    const int g = xcd * gpx + (j >> 2);
    const int ytile = g & 3;
    const int z = g >> 2;
    const int c0 = xtile * 128, d0 = ytile * 128;
    const int b = z >> 3, nch = z & 7;

    const int w = tid >> 6, l = tid & 63;
    const int lr = l >> 2, lg = l & 3;
    const int rA0 = w * 32 + lr, rA1 = w * 32 + 16 + lr;
    const int gA0 = lg ^ ((rA0 >> 1) & 3), gA1 = lg ^ ((rA1 >> 1) & 3);
    const ushort_t* Ab = v0c + (long)b * CN_ + nch * 512;
    const ushort_t* Bb = khat + (long)b * CN_ + nch * 512;
    const ushort_t* ap0 = Ab + (long)(d0 + rA0) * N_DIM + gA0 * 8;
    const ushort_t* ap1 = Ab + (long)(d0 + rA1) * N_DIM + gA1 * 8;
    const ushort_t* bp0 = Bb + (long)(c0 + rA0) * N_DIM + gA0 * 8;
    const ushort_t* bp1 = Bb + (long)(c0 + rA1) * N_DIM + gA1 * 8;
    const int la0 = (w * 32) * 32, la1 = (w * 32 + 16) * 32;

    const int wr = (w >> 1) * 64, wc = (w & 1) * 64;
    const int fr = l & 15, ks = l >> 4;
    const int rsw = (ks ^ ((fr >> 1) & 3)) << 3;

    f32x4 acc[4][4];
#pragma unroll
    for (int m = 0; m < 4; ++m)
#pragma unroll
        for (int nf = 0; nf < 4; ++nf) acc[m][nf] = f32x4{0.f, 0.f, 0.f, 0.f};

    KLOOP(512);

    float* KV = kvp + ((long)(nch * 4 + b)) * 262144;
#pragma unroll
    for (int m = 0; m < 4; ++m)
#pragma unroll
        for (int nf = 0; nf < 4; ++nf) {
            const int cc = c0 + wc + nf * 16 + fr;
#pragma unroll
            for (int j2 = 0; j2 < 4; ++j2) {
                const int dd = d0 + wr + m * 16 + ks * 4 + j2;
                KV[(long)dd * 512 + cc] = acc[m][nf][j2];
            }
        }
}

// kvT[i] = f2b( (1/sqrt(512)) * sum_nch kvp[nch][i] )
__global__ __launch_bounds__(256) void cvt_scale8(
    const float* __restrict__ kvp, ushort_t* __restrict__ out)
{
    const float s = 0.044194173824159216f;
    const long i = ((long)blockIdx.x * 256 + threadIdx.x) * 4;
    const int b = (int)(i >> 18);
    const long j = i & 262143;
    float4 a = make_float4(0.f, 0.f, 0.f, 0.f);
#pragma unroll
    for (int nch = 0; nch < 8; ++nch) {
        float4 v = *(const float4*)&kvp[((long)(nch * 4 + b)) * 262144 + j];
        a.x += v.x; a.y += v.y; a.z += v.z; a.w += v.w;
    }
    union { ushort_t sh[4]; uint2 u; } p;
    p.sh[0] = f2b(a.x * s); p.sh[1] = f2b(a.y * s);
    p.sh[2] = f2b(a.z * s); p.sh[3] = f2b(a.w * s);
    *(uint2*)&out[i] = p.u;
}

// ---------------------------------------------------------------------------
// fused Wphi + ybar, INTERLEAVED, counted vmcnt (8 loads/tile in flight)
// ---------------------------------------------------------------------------
__global__ __launch_bounds__(256, 2) void ybar_gemm(
    const ushort_t* __restrict__ q12, const ushort_t* __restrict__ kvT,
    const ushort_t* __restrict__ xT12, const ushort_t* __restrict__ Wphi_b,
    const float* __restrict__ den12, ushort_t* __restrict__ y12)
{
    __shared__ ushort_t Als[2][128 * 32];
    __shared__ ushort_t Bls[2][128 * 32];
    __shared__ ushort_t Cls[2][128 * 32];
    __shared__ ushort_t Dls[2][128 * 32];
    const int tid = threadIdx.x;
    const int L = blockIdx.x;
    const int gpx = (gridDim.x >> 3) >> 2;
    const int xcd = L & 7;
    const int j = L >> 3;
    const int xtile = j & 3;
    const int g = xcd * gpx + (j >> 2);
    const int ytile = g & 31;
    const int mm = g >> 5;
    const int o0 = xtile * 128, n0 = ytile * 128;

    const int w = tid >> 6, l = tid & 63;
    const int lr = l >> 2, lg = l & 3;
    const int rA0 = w * 32 + lr, rA1 = w * 32 + 16 + lr;
    const int gA0 = lg ^ ((rA0 >> 1) & 3), gA1 = lg ^ ((rA1 >> 1) & 3);
    const long aoff0 = (long)(n0 + rA0) * 512 + gA0 * 8;
    const long aoff1 = (long)(n0 + rA1) * 512 + gA1 * 8;
    const long boff0 = (long)(o0 + rA0) * 512 + gA0 * 8;
    const long boff1 = (long)(o0 + rA1) * 512 + gA1 * 8;
    const int la0 = (w * 32) * 32, la1 = (w * 32 + 16) * 32;

    const int wr = (w >> 1) * 64, wc = (w & 1) * 64;
    const int fr = l & 15, ks = l >> 4;
    const int rsw = (ks ^ ((fr >> 1) & 3)) << 3;

    const ushort_t* pa0 = xT12 + (long)mm * CN_ + aoff0;
    const ushort_t* pa1 = xT12 + (long)mm * CN_ + aoff1;
    const ushort_t* pb0 = Wphi_b + boff0;
    const ushort_t* pb1 = Wphi_b + boff1;
    const ushort_t* qa0 = q12 + (long)mm * CN_ + aoff0;
    const ushort_t* qa1 = q12 + (long)mm * CN_ + aoff1;
    const ushort_t* kb0 = kvT + (long)(mm & 3) * 262144 + boff0;
    const ushort_t* kb1 = kvT + (long)(mm & 3) * 262144 + boff1;

    f32x4 accP[4][4], accQ[4][4];
#pragma unroll
    for (int m = 0; m < 4; ++m)
#pragma unroll
        for (int nf = 0; nf < 4; ++nf) {
            accP[m][nf] = f32x4{0.f, 0.f, 0.f, 0.f};
            accQ[m][nf] = f32x4{0.f, 0.f, 0.f, 0.f};
        }

#define STAGE2(q, koff) { \
    GLOAD(pa0 + (koff), &Als[q][la0]); GLOAD(pa1 + (koff), &Als[q][la1]); \
    GLOAD(pb0 + (koff), &Bls[q][la0]); GLOAD(pb1 + (koff), &Bls[q][la1]); \
    GLOAD(qa0 + (koff), &Cls[q][la0]); GLOAD(qa1 + (koff), &Cls[q][la1]); \
    GLOAD(kb0 + (koff), &Dls[q][la0]); GLOAD(kb1 + (koff), &Dls[q][la1]); }

#define COMPUTE2(q) { \
    bf16x8 af[4], bfv[4], cf[4], df[4]; \
    _Pragma("unroll") for (int m_ = 0; m_ < 4; ++m_) { \
        af[m_] = *(const bf16x8*)&Als[q][(wr + m_ * 16 + fr) * 32 + rsw]; \
        cf[m_] = *(const bf16x8*)&Cls[q][(wr + m_ * 16 + fr) * 32 + rsw]; } \
    _Pragma("unroll") for (int nf_ = 0; nf_ < 4; ++nf_) { \
        bfv[nf_] = *(const bf16x8*)&Bls[q][(wc + nf_ * 16 + fr) * 32 + rsw]; \
        df[nf_] = *(const bf16x8*)&Dls[q][(wc + nf_ * 16 + fr) * 32 + rsw]; } \
    __builtin_amdgcn_s_setprio(1); \
    _Pragma("unroll") for (int m_ = 0; m_ < 4; ++m_) \
        _Pragma("unroll") for (int nf_ = 0; nf_ < 4; ++nf_) { \
            accP[m_][nf_] = __builtin_amdgcn_mfma_f32_16x16x32_bf16( \
                af[m_], bfv[nf_], accP[m_][nf_], 0, 0, 0); \
            accQ[m_][nf_] = __builtin_amdgcn_mfma_f32_16x16x32_bf16( \
                cf[m_], df[nf_], accQ[m_][nf_], 0, 0, 0); } \
    __builtin_amdgcn_s_setprio(0); }

    STAGE2(0, 0);
    STAGE2(1, 32);
    int s_ = 0;
    while (true) {
        if (s_ + 1 < 16) { WAITV8 } else { WAITV0 }
        SBAR;
        COMPUTE2(s_ & 1);
        SBAR;
        if (s_ + 2 < 16) STAGE2(s_ & 1, (s_ + 2) * 32);
        ++s_;
        if (s_ >= 16) break;
    }
#undef STAGE2
#undef COMPUTE2

    const float* D = den12 + (long)mm * N_DIM;
    ushort_t* Y = y12 + (long)mm * CN_;
#pragma unroll
    for (int m = 0; m < 4; ++m) {
        float zr[4];
#pragma unroll
        for (int j2 = 0; j2 < 4; ++j2)
            zr[j2] = 1.f / (D[n0 + wr + m * 16 + ks * 4 + j2] + 1e-6f);
#pragma unroll
        for (int nf = 0; nf < 4; ++nf) {
            const int oo = o0 + wc + nf * 16 + fr;
#pragma unroll
            for (int j2 = 0; j2 < 4; ++j2) {
                const int nn = n0 + wr + m * 16 + ks * 4 + j2;
                Y[(long)nn * 512 + oo] = f2b(accQ[m][nf][j2] * zr[j2] * accP[m][nf][j2]);
            }
        }
    }
}

// ybar stage B: ybar[i] = (1/12) sum_mm y12[mm][i]
__global__ __launch_bounds__(256) void ybar_reduce(
    const ushort_t* __restrict__ y12, float* __restrict__ ybar)
{
    const long i = ((long)blockIdx.x * 256 + threadIdx.x) * 8;
    float s[8] = {0.f, 0.f, 0.f, 0.f, 0.f, 0.f, 0.f, 0.f};
    for (int mm = 0; mm < 12; ++mm) {
        uint4 u = *(const uint4*)&y12[(long)mm * CN_ + i];
        const ushort_t* us = (const ushort_t*)&u;
#pragma unroll
        for (int j = 0; j < 8; ++j) s[j] += b2f(us[j]);
    }
#pragma unroll
    for (int j = 0; j < 8; ++j) s[j] *= (1.f / 12.f);
    *(float4*)&ybar[i] = make_float4(s[0], s[1], s[2], s[3]);
    *(float4*)&ybar[i + 4] = make_float4(s[4], s[5], s[6], s[7]);
}

// bf16 [z][4096][512] -> bf16 [z][512][4096]; ALPHA: out *= alpha[z][n],
// and ksum[z][c] += sum_n t[n][c]*alpha[n] (atomicAdd; pre-zeroed).
template<int ALPHA>
__global__ __launch_bounds__(256) void transpose_b2b(
    const ushort_t* __restrict__ in, ushort_t* __restrict__ out,
    const float* __restrict__ alpha, float* __restrict__ ksum)
{
    __shared__ ushort_t t[64][72];
    const int tid = threadIdx.x;
    const int n0 = blockIdx.x * 64, c0 = blockIdx.y * 64, z = blockIdx.z;
    const ushort_t* I = in + (long)z * CN_;
    ushort_t* O = out + (long)z * CN_;
    const int r = tid >> 2, s8 = (tid & 3) * 16;
    uint4 u0 = *(const uint4*)&I[(long)(n0 + r) * 512 + c0 + s8];
    uint4 u1 = *(const uint4*)&I[(long)(n0 + r) * 512 + c0 + s8 + 8];
    *(uint4*)&t[r][s8] = u0;
    *(uint4*)&t[r][s8 + 8] = u1;
    __syncthreads();
    union { ushort_t sh[16]; uint4 u[2]; } p;
#pragma unroll
    for (int i = 0; i < 16; ++i) {
        ushort_t v = t[s8 + i][r];
        if (ALPHA) v = f2b(b2f(v) * alpha[(long)z * N_DIM + n0 + s8 + i]);
        p.sh[i] = v;
    }
    uint4* dst = (uint4*)&O[(long)(c0 + r) * N_DIM + n0 + s8];
    dst[0] = p.u[0]; dst[1] = p.u[1];
    if (ALPHA) {
        const int c = tid & 63, q = tid >> 6;
        float s = 0.f;
#pragma unroll
        for (int i = 0; i < 16; ++i) {
            const int n = q * 16 + i;
            s += b2f(t[n][c]) * alpha[(long)z * N_DIM + n0 + n];
        }
        atomicAdd(&ksum[((long)z << 9) + c0 + c], s);
    }
}

// all-weights fp32 -> bf16 in one dispatch
__global__ __launch_bounds__(256) void cvt_all(
    const float* __restrict__ s0, ushort_t* __restrict__ d0,
    const float* __restrict__ s1, ushort_t* __restrict__ d1,
    const float* __restrict__ s2, ushort_t* __restrict__ d2,
    const float* __restrict__ s3, ushort_t* __restrict__ d3,
    const float* __restrict__ s4, ushort_t* __restrict__ d4,
    const float* __restrict__ s5, ushort_t* __restrict__ d5)
{
    long i = ((long)blockIdx.x * 256 + threadIdx.x) * 4;
    const float* s; ushort_t* d; long off;
    if (i < 65536)        { s = s0; d = d0; off = i; }
    else if (i < 131072)  { s = s1; d = d1; off = i - 65536; }
    else if (i < 393216)  { s = s2; d = d2; off = i - 131072; }
    else if (i < 655360)  { s = s3; d = d3; off = i - 393216; }
    else if (i < 1703936) { s = s4; d = d4; off = i - 655360; }
    else                  { s = s5; d = d5; off = i - 1703936; }
    float4 v = *(const float4*)&s[off];
    union { ushort_t sh[4]; uint2 u; } p;
    p.sh[0] = f2b(v.x); p.sh[1] = f2b(v.y); p.sh[2] = f2b(v.z); p.sh[3] = f2b(v.w);
    *(uint2*)&d[off] = p.u;
}

// transpose fp32 x[z][512][4096] -> bf16 xT[z][4096][512].
// 128x128 tiles; bf16 staged in LDS (pad-132 rows); 256B write segments.
// PASSZ: for z>=4 also stream the raw fp32 tile to passout (passthrough).
template<int PASSZ>
__global__ __launch_bounds__(256) void transpose_f2b(
    const float* __restrict__ in, ushort_t* __restrict__ out,
    float* __restrict__ passout)
{
    __shared__ ushort_t t[128 * 132];
    const int tid = threadIdx.x;
    const int n0 = blockIdx.x * 128, c0 = blockIdx.y * 128;
    const int z = blockIdx.z;
    const int r = tid >> 1, h = (tid & 1) * 64;
    const float* src = in + (long)z * CN_ + (long)(c0 + r) * N_DIM + n0 + h;
    float* P = passout + (long)z * CN_ + (long)(c0 + r) * N_DIM + n0 + h;
    const bool dopass = PASSZ && (z >= 4);
#pragma unroll
    for (int i = 0; i < 16; ++i) {
        float4 v = *(const float4*)&src[i * 4];
        if (dopass) *(float4*)&P[i * 4] = v;
        union { ushort_t sh[4]; uint2 u; } pk;
        pk.sh[0] = f2b(v.x); pk.sh[1] = f2b(v.y);
        pk.sh[2] = f2b(v.z); pk.sh[3] = f2b(v.w);
        *(uint2*)&t[r * 132 + h + i * 4] = pk.u;
    }
    __syncthreads();
    ushort_t* dst = out + (long)z * CN_ + (long)(n0 + r) * C_DIM + c0 + h;
#pragma unroll
    for (int i = 0; i < 8; ++i) {
        union { ushort_t sh[8]; uint4 u; } pk;
#pragma unroll
        for (int jj = 0; jj < 8; ++jj) pk.sh[jj] = t[(h + i * 8 + jj) * 132 + r];
        *(uint4*)&dst[i * 8] = pk.u;
    }
}

// out[z][n] = scale * sum_c X[z][n][c] * w[(z&3)][c]
__global__ __launch_bounds__(256) void dot_rows(
    const ushort_t* __restrict__ X, const float* __restrict__ w,
    float* __restrict__ out, float scale)
{
    const int tid = threadIdx.x;
    const int rn = tid >> 2, cs = (tid & 3) * 128;
    const int z = blockIdx.y;
    const int n = blockIdx.x * 64 + rn;
    const ushort_t* row = X + (long)z * CN_ + (long)n * C_DIM;
    const float* wz = w + (long)(z & 3) * C_DIM;
    float s = 0.f;
    for (int i = 0; i < 128; i += 8) {
        uint4 u = *(const uint4*)&row[cs + i];
        const ushort_t* us = (const ushort_t*)&u;
#pragma unroll
        for (int k2 = 0; k2 < 8; ++k2) s += b2f(us[k2]) * wz[cs + i + k2];
    }
    s += __shfl_xor(s, 1); s += __shfl_xor(s, 2);
    if ((tid & 3) == 0) out[(long)z * N_DIM + n] = s * scale;
}

// alpha[b,n] = softmax_n(logits[b,:]) * N
__global__ __launch_bounds__(256) void softmax_alpha(
    const float* __restrict__ logits, float* __restrict__ alpha)
{
    int b = blockIdx.x, tid = threadIdx.x;
    const float* L = logits + (long)b * N_DIM;
    float* A = alpha + (long)b * N_DIM;
    float lv[16];
    float mx = -3.4e38f;
#pragma unroll
    for (int i = 0; i < 4; i++) {
        float4 v = *(const float4*)&L[tid * 4 + i * 1024];
        lv[4 * i + 0] = v.x; lv[4 * i + 1] = v.y; lv[4 * i + 2] = v.z; lv[4 * i + 3] = v.w;
        mx = fmaxf(mx, fmaxf(fmaxf(v.x, v.y), fmaxf(v.z, v.w)));
    }
    __shared__ float red[8];
    float m = mx;
#pragma unroll
    for (int off = 32; off; off >>= 1) m = fmaxf(m, __shfl_down(m, off, 64));
    int wid = tid >> 6, lane = tid & 63;
    if (lane == 0) red[wid] = m;
    __syncthreads();
    m = fmaxf(fmaxf(red[0], red[1]), fmaxf(red[2], red[3]));
    float e[16], s = 0.f;
#pragma unroll
    for (int i = 0; i < 16; i++) { e[i] = expf(lv[i] - m); s += e[i]; }
#pragma unroll
    for (int off = 32; off; off >>= 1) s += __shfl_down(s, off, 64);
    if (lane == 0) red[4 + wid] = s;
    __syncthreads();
    float S = red[4] + red[5] + red[6] + red[7];
    float sc = 4096.f / S;
#pragma unroll
    for (int i = 0; i < 4; i++)
        *(float4*)&A[tid * 4 + i * 1024] =
            make_float4(e[4 * i] * sc, e[4 * i + 1] * sc, e[4 * i + 2] * sc, e[4 * i + 3] * sc);
}

// row LayerNorm over c (512) per (z,n); IBF: bf16 input; OBF: bf16 output
template<int RELU, int OBF, int IBF>
__global__ __launch_bounds__(256) void ln_row(
    const void* __restrict__ inv, const float* __restrict__ g,
    const float* __restrict__ bt, void* __restrict__ outv)
{
    const int tid = threadIdx.x;
    const int r = tid >> 3, cs = (tid & 7) * 64;
    const long base = (((long)blockIdx.y * N_DIM) + blockIdx.x * 32 + r) * C_DIM + cs;
    float vv[64];
    float s = 0.f, s2 = 0.f;
    if (IBF) {
        const ushort_t* I = (const ushort_t*)inv + base;
#pragma unroll
        for (int i = 0; i < 8; ++i) {
            uint4 u = *(const uint4*)&I[i * 8];
            const ushort_t* us = (const ushort_t*)&u;
#pragma unroll
            for (int jj = 0; jj < 8; ++jj) {
                float f = b2f(us[jj]); vv[i * 8 + jj] = f; s += f; s2 += f * f;
            }
        }
    } else {
        const float* I = (const float*)inv + base;
#pragma unroll
        for (int i = 0; i < 16; ++i) {
            float4 v = *(const float4*)&I[i * 4];
            vv[i * 4] = v.x; vv[i * 4 + 1] = v.y; vv[i * 4 + 2] = v.z; vv[i * 4 + 3] = v.w;
            s += v.x + v.y + v.z + v.w;
            s2 += v.x * v.x + v.y * v.y + v.z * v.z + v.w * v.w;
        }
    }
#pragma unroll
    for (int off = 1; off < 8; off <<= 1) { s += __shfl_xor(s, off); s2 += __shfl_xor(s2, off); }
    const float mean = s * (1.f / 512.f);
    const float var = s2 * (1.f / 512.f) - mean * mean;
    const float rs = rsqrtf(var + 1e-6f);
#pragma unroll
    for (int i = 0; i < 64; i += 4) {
        float o[4];
#pragma unroll
        for (int jj = 0; jj < 4; ++jj) {
            float ov = (vv[i + jj] - mean) * rs * g[cs + i + jj] + bt[cs + i + jj];
            if (RELU) ov = fmaxf(ov, 0.f);
            o[jj] = ov;
        }
        if (OBF) {
            union { ushort_t s4[4]; uint2 u; } p;
            p.s4[0] = f2b(o[0]); p.s4[1] = f2b(o[1]); p.s4[2] = f2b(o[2]); p.s4[3] = f2b(o[3]);
            *(uint2*)&((ushort_t*)outv)[base + i] = p.u;
        } else {
            *(float4*)&((float*)outv)[base + i] = make_float4(o[0], o[1], o[2], o[3]);
        }
    }
}

// fused LN2 + relu + transpose: in bf16 [z][n][c] -> out fp32 [z][c][n]
__global__ __launch_bounds__(256) void ln_tr(
    const ushort_t* __restrict__ in, const float* __restrict__ g,
    const float* __restrict__ bt, float* __restrict__ out)
{
    __shared__ float t[32][513];
    const int tid = threadIdx.x;
    const int r = tid >> 3;
    const int lc = (tid & 7) * 8;
    const int z = blockIdx.y;
    const long n = (long)blockIdx.x * 32 + r;
    const ushort_t* I = in + ((long)z * N_DIM + n) * C_DIM;
    float vv[64];
    float s = 0.f, s2 = 0.f;
#pragma unroll
    for (int i = 0; i < 8; ++i) {
        const int c = i * 64 + lc;
        uint4 u = *(const uint4*)&I[c];
        const ushort_t* us = (const ushort_t*)&u;
#pragma unroll
        for (int jj = 0; jj < 8; ++jj) {
            float f = b2f(us[jj]); vv[i * 8 + jj] = f; s += f; s2 += f * f;
        }
    }
#pragma unroll
    for (int off = 1; off < 8; off <<= 1) { s += __shfl_xor(s, off); s2 += __shfl_xor(s2, off); }
    const float mean = s * (1.f / 512.f);
    const float var = s2 * (1.f / 512.f) - mean * mean;
    const float rs = rsqrtf(var + 1e-6f);
#pragma unroll
    for (int i = 0; i < 8; ++i) {
        const int c = i * 64 + lc;
#pragma unroll
        for (int jj = 0; jj < 8; ++jj) {
            float o = (vv[i * 8 + jj] - mean) * rs * g[c + jj] + bt[c + jj];
            t[r][c + jj] = fmaxf(o, 0.f);
        }
    }
    __syncthreads();
    float* O = out + (long)z * CN_ + (long)blockIdx.x * 32;
    for (int c = tid; c < 512; c += 256) {
        float* dst = O + (long)c * N_DIM;
#pragma unroll
        for (int i = 0; i < 32; i += 4)
            *(float4*)&dst[i] = make_float4(t[i][c], t[i + 1][c], t[i + 2][c], t[i + 3][c]);
    }
}

extern "C" void kernel_launch(void* const* d_in, const int* in_sizes, int n_in,
                              void* d_out, int out_size, void* d_ws, size_t ws_size,
                              hipStream_t stream)
{
    const float* x     = (const float*)d_in[0];
    const float* Wq    = (const float*)d_in[1];
    const float* Wk    = (const float*)d_in[2];
    const float* Wv    = (const float*)d_in[3];
    const float* Wphi  = (const float*)d_in[4];
    const float* ln1_w = (const float*)d_in[5];
    const float* ln1_b = (const float*)d_in[6];
    const float* fc1_w = (const float*)d_in[7];
    const float* fc1_bias = (const float*)d_in[8];
    const float* fc2_w = (const float*)d_in[9];
    const float* fc2_bias = (const float*)d_in[10];
    const float* ln2_w = (const float*)d_in[11];
    const float* ln2_b = (const float*)d_in[12];
    float* out = (float*)d_out;

    float* ws = (float*)d_ws;
    const long CN = CN_;
    // region map (float units); lifetimes are stream-sequential:
    ushort_t* xTfirst = (ushort_t*)ws;                 // [0,2CN)  (tln later)
    ushort_t* tln     = (ushort_t*)ws;
    ushort_t* xT12 = (ushort_t*)(ws + 2 * CN);         // [2CN,8CN)
    ushort_t* hbuf4 = (ushort_t*)(ws + 2 * CN);        // stage3 reuse [2CN,6CN)
    ushort_t* q12   = (ushort_t*)(ws + 8 * CN);        // [8CN,14CN)
    ushort_t* y12   = (ushort_t*)(ws + 14 * CN);       // [14CN,20CN)
    ushort_t* k0b = (ushort_t*)(ws + 20 * CN);         // [20CN,22CN) stage1
    ushort_t* v0b = (ushort_t*)(ws + 22 * CN);         // [22CN,24CN) stage1
    ushort_t* pre_b = (ushort_t*)(ws + 20 * CN);       // stage3 reuse
    ushort_t* khat = (ushort_t*)(ws + 24 * CN);        // [24CN,26CN) stage1
    ushort_t* v0c  = (ushort_t*)(ws + 26 * CN);        // [26CN,28CN) stage1
    ushort_t* ubuf_b = (ushort_t*)(ws + 24 * CN);      // stage3 reuse
    float* ybar = ws + 32 * CN;                        // [32CN,33CN)
    float* kvp  = ws + 33 * CN;                        // 8388608 floats
    ushort_t* kvT = (ushort_t*)(ws + 33 * CN + 8388608);
    float* wb = ws + 33 * CN + 8388608 + 524288;
    ushort_t* Wk_b   = (ushort_t*)(wb);
    ushort_t* Wq_b   = (ushort_t*)(wb + 32768);
    ushort_t* Wv_b   = (ushort_t*)(wb + 65536);
    ushort_t* Wphi_b = (ushort_t*)(wb + 196608);
    ushort_t* fc1_b16 = (ushort_t*)(wb + 327680);
    ushort_t* fc2_b16 = (ushort_t*)(wb + 851968);
    float* Qg     = wb + 1376256;                      // 2048
    float* ksum   = wb + 1378304;                      // 2048
    float* logits = wb + 1380352;
    float* alpha  = wb + 1396736;
    float* den12  = wb + 1413120;                      // 49152

    dim3 blk(256);

    // all weights -> bf16; zero atomic accumulators
    cvt_all<<<2688, blk, 0, stream>>>(Wk, Wk_b, Wq, Wq_b, Wv, Wv_b,
                                      Wphi, Wphi_b, fc1_w, fc1_b16, fc2_w, fc2_b16);
    hipMemsetAsync(Qg, 0, 4096 * sizeof(float), stream);        // Qg + ksum
    hipMemsetAsync(den12, 0, 49152 * sizeof(float), stream);

    // all 16 batches transposed; z>=4 also writes raw x to out (passthrough)
    transpose_f2b<1><<<dim3(32, 4, 16), blk, 0, stream>>>(x, xTfirst, out);

    // stage 1: k0 (+Qg fused), v0, logits, alpha, khat (+ksum fused), v0c, kv
    mfma_gemm<EPI_PHI, true, true, false, true><<<512, blk, 0, stream>>>(
        Wk_b, xTfirst, k0b, nullptr, nullptr, Qg, 128, 512, 512, CN, CN, 0, 4, 32);
    mfma_gemm<EPI_NONE, false, true, false, false><<<512, blk, 0, stream>>>(
        Wv_b, xTfirst, v0b, nullptr, nullptr, nullptr, 512, 512, 512, CN, CN, 0, 4, 32);
    dot_rows<<<dim3(64, 4), blk, 0, stream>>>(k0b, Qg, logits, 1.f / 4096.f);
    softmax_alpha<<<4, blk, 0, stream>>>(logits, alpha);
    transpose_b2b<1><<<dim3(64, 8, 4), blk, 0, stream>>>(k0b, khat, alpha, ksum);
    transpose_b2b<0><<<dim3(64, 8, 4), blk, 0, stream>>>(v0b, v0c, nullptr, nullptr);
    kv_mfma<<<512, blk, 0, stream>>>(v0c, khat, kvp);
    cvt_scale8<<<1024, blk, 0, stream>>>(kvp, kvT);

    // stage 2: q (with fused den), interleaved phi+ybar, reduce
    mfma_gemm<EPI_PHI, true, true, true, false><<<1536, blk, 0, stream>>>(
        Wq_b, xT12, q12, ksum, nullptr, den12, 128, 512, 512, CN, CN, 0, 4, 32);
    ybar_gemm<<<1536, blk, 0, stream>>>(q12, kvT, xT12, Wphi_b, den12, y12);
    ybar_reduce<<<1024, blk, 0, stream>>>(y12, ybar);

    // stage 3: pre(bf16) = firstT + ybar*phiF; LN1; MLP; fused LN2+relu+transpose
    mfma_gemm<EPI_PRE, false, true, false, false><<<512, blk, 0, stream>>>(
        Wphi_b, xTfirst, pre_b, nullptr, xTfirst, ybar, 512, 512, 512, CN, CN, CN, 4, 32);
    ln_row<0, 1, 1><<<dim3(128, 4), blk, 0, stream>>>(pre_b, ln1_w, ln1_b, tln);
    mfma_gemm<EPI_RELU_BIAS, false, true, false, false><<<2048, blk, 0, stream>>>(
        fc1_b16, tln, hbuf4, fc1_bias, nullptr, nullptr,
        512, 2048, 512, CN, 8388608, 0, 16, 32);
    mfma_gemm<EPI_RES_BIAS, false, true, false, false><<<512, blk, 0, stream>>>(
        fc2_b16, hbuf4, ubuf_b, fc2_bias, tln, nullptr,
        2048, 512, 2048, 8388608, CN, CN, 4, 32);
    ln_tr<<<dim3(128, 4), blk, 0, stream>>>(ubuf_b, ln2_w, ln2_b, out);
}

// Round 18
// 536.064 us; speedup vs baseline: 1.0849x; 1.0849x over previous
//
#include <hip/hip_runtime.h>

#define N_DIM 4096
#define C_DIM 512
#define CN_ ((long)C_DIM * (long)N_DIM)   // 2,097,152

typedef unsigned short ushort_t;
typedef __attribute__((ext_vector_type(8))) short bf16x8;
typedef __attribute__((ext_vector_type(4))) float f32x4;

typedef const __attribute__((address_space(1))) unsigned int* gas_t;
typedef __attribute__((address_space(3))) unsigned int* las_t;
#define GLOAD(g, l) __builtin_amdgcn_global_load_lds((gas_t)(g), (las_t)(l), 16, 0, 0)

__device__ __forceinline__ ushort_t f2b(float f) {
    unsigned u = __builtin_bit_cast(unsigned, f);
    u += 0x7fffu + ((u >> 16) & 1u);
    return (ushort_t)(u >> 16);
}
__device__ __forceinline__ float b2f(ushort_t s) {
    return __builtin_bit_cast(float, (unsigned)s << 16);
}

enum { EPI_NONE = 0, EPI_PHI = 1, EPI_RELU_BIAS = 2, EPI_RES_BIAS = 3, EPI_PRE = 4 };

// raw barrier + scheduler fences (rule #18 / m152 discipline)
#define SBAR { __builtin_amdgcn_sched_barrier(0); __builtin_amdgcn_s_barrier(); __builtin_amdgcn_sched_barrier(0); }
#define WAITV0 { asm volatile("s_waitcnt vmcnt(0)" ::: "memory"); __builtin_amdgcn_sched_barrier(0); }
#define WAITV4 { asm volatile("s_waitcnt vmcnt(4)" ::: "memory"); __builtin_amdgcn_sched_barrier(0); }
#define WAITV8 { asm volatile("s_waitcnt vmcnt(8)" ::: "memory"); __builtin_amdgcn_sched_barrier(0); }

// Shared K-loop: 128x128 tile, 4 waves, BK=32, two LDS stage buffers.
// Counted vmcnt: next tile's 4 global_load_lds stay in flight across both
// barriers (T4); only the tail drains to 0.
#define STAGE(q, koff) { \
    GLOAD(ap0 + (koff), &Als[q][la0]); \
    GLOAD(ap1 + (koff), &Als[q][la1]); \
    GLOAD(bp0 + (koff), &Bls[q][la0]); \
    GLOAD(bp1 + (koff), &Bls[q][la1]); }

#define COMPUTE(q) { \
    bf16x8 af[4], bfv[4]; \
    _Pragma("unroll") for (int m_ = 0; m_ < 4; ++m_) \
        af[m_] = *(const bf16x8*)&Als[q][(wr + m_ * 16 + fr) * 32 + rsw]; \
    _Pragma("unroll") for (int nf_ = 0; nf_ < 4; ++nf_) \
        bfv[nf_] = *(const bf16x8*)&Bls[q][(wc + nf_ * 16 + fr) * 32 + rsw]; \
    _Pragma("unroll") for (int m_ = 0; m_ < 4; ++m_) \
        _Pragma("unroll") for (int nf_ = 0; nf_ < 4; ++nf_) \
            acc[m_][nf_] = __builtin_amdgcn_mfma_f32_16x16x32_bf16( \
                af[m_], bfv[nf_], acc[m_][nf_], 0, 0, 0); }

#define KLOOP(K_) { \
    const int S_ = (K_) / 32; \
    STAGE(0, 0); \
    if (S_ > 1) STAGE(1, 32); \
    int s_ = 0; \
    while (true) { \
        if (s_ + 1 < S_) { WAITV4 } else { WAITV0 } \
        SBAR; \
        COMPUTE(s_ & 1); \
        SBAR; \
        if (s_ + 2 < S_) STAGE(s_ & 1, (s_ + 2) * 32); \
        ++s_; \
        if (s_ >= S_) break; \
    } }

// ---------------------------------------------------------------------------
// bf16 MFMA GEMM: OUT[z][n][o] = epi( sum_k A[z][n][k] * W[o][k] )
// DEN: den[z][n] += sum_o v * ksum[(z&3)][o]  (ksum in bias, den in auxf)
// QGS: qg[z][o] += sum_n v  (qg in auxf; pre-zeroed)
// ---------------------------------------------------------------------------
template<int EPI, bool GROUPED, bool OBF, bool DEN, bool QGS>
__global__ __launch_bounds__(256, 3) void mfma_gemm(
    const ushort_t* __restrict__ Wb, const ushort_t* __restrict__ A,
    void* __restrict__ OUTV, const float* __restrict__ bias,
    const ushort_t* __restrict__ auxb, const float* __restrict__ auxf,
    int K, int O, int a_rstride, long a_zstride, long o_zstride, long auxb_zstride,
    int xt, int yt)
{
    __shared__ ushort_t Als[2][128 * 32];
    __shared__ ushort_t Bls[2][128 * 32];
    const int tid = threadIdx.x;

    const int L = blockIdx.x;
    const int gpx = (gridDim.x >> 3) / xt;
    const int xcd = L & 7;
    const int j = L >> 3;
    const int xtile = j % xt;
    const int g = xcd * gpx + j / xt;
    const int ytile = g % yt;
    const int z = g / yt;

    const int o0 = xtile * 128;
    const int n0 = ytile * 128;
    const ushort_t* Az = A + (long)z * a_zstride;
    const ushort_t* Wp = Wb;
    int kbase = 0, obase = o0;
    if (GROUPED) { int gg = o0 >> 7; Wp = Wb + (long)gg * (128 * 128); kbase = gg << 7; obase = 0; }

    const int w = tid >> 6, l = tid & 63;
    const int lr = l >> 2, lg = l & 3;
    const int rA0 = w * 32 + lr, rA1 = w * 32 + 16 + lr;
    const int gA0 = lg ^ ((rA0 >> 1) & 3), gA1 = lg ^ ((rA1 >> 1) & 3);
    const ushort_t* ap0 = Az + (long)(n0 + rA0) * a_rstride + kbase + gA0 * 8;
    const ushort_t* ap1 = Az + (long)(n0 + rA1) * a_rstride + kbase + gA1 * 8;
    const ushort_t* bp0 = Wp + (long)(obase + rA0) * K + gA0 * 8;
    const ushort_t* bp1 = Wp + (long)(obase + rA1) * K + gA1 * 8;
    const int la0 = (w * 32) * 32, la1 = (w * 32 + 16) * 32;

    const int wr = (w >> 1) * 64, wc = (w & 1) * 64;
    const int fr = l & 15, ks = l >> 4;
    const int rsw = (ks ^ ((fr >> 1) & 3)) << 3;

    f32x4 acc[4][4];
#pragma unroll
    for (int m = 0; m < 4; ++m)
#pragma unroll
        for (int nf = 0; nf < 4; ++nf) acc[m][nf] = f32x4{0.f, 0.f, 0.f, 0.f};

    KLOOP(K);

    float dsum[4][4];
    if (DEN) {
#pragma unroll
        for (int m = 0; m < 4; ++m)
#pragma unroll
            for (int j2 = 0; j2 < 4; ++j2) dsum[m][j2] = 0.f;
    }
    float qsum[4];
    if (QGS) {
#pragma unroll
        for (int nf = 0; nf < 4; ++nf) qsum[nf] = 0.f;
    }

#pragma unroll
    for (int m = 0; m < 4; ++m) {
#pragma unroll
        for (int nf = 0; nf < 4; ++nf) {
            const int oo = o0 + wc + nf * 16 + fr;
            float bval = 0.f;
            if (EPI == EPI_RELU_BIAS || EPI == EPI_RES_BIAS) bval = bias[oo];
            float kw = 0.f;
            if (DEN) kw = bias[((z & 3) << 9) + oo];
#pragma unroll
            for (int j2 = 0; j2 < 4; ++j2) {
                const int nn = n0 + wr + m * 16 + ks * 4 + j2;
                const long ridx = (long)nn * O + oo;
                float v = acc[m][nf][j2];
                if (EPI == EPI_PHI)            v = fmaxf(v, 0.f) + 1.f;
                else if (EPI == EPI_RELU_BIAS) v = fmaxf(v + bval, 0.f);
                else if (EPI == EPI_RES_BIAS)  v = v + bval + b2f(auxb[(long)z * auxb_zstride + ridx]);
                else if (EPI == EPI_PRE)       v = b2f(auxb[(long)z * auxb_zstride + ridx]) + auxf[ridx] * v;
                if (DEN) dsum[m][j2] += v * kw;
                if (QGS) qsum[nf] += v;
                if (OBF) ((ushort_t*)OUTV)[(long)z * o_zstride + ridx] = f2b(v);
                else     ((float*)OUTV)[(long)z * o_zstride + ridx] = v;
            }
        }
    }

    if (DEN) {
#pragma unroll
        for (int m = 0; m < 4; ++m)
#pragma unroll
            for (int j2 = 0; j2 < 4; ++j2) {
                float d = dsum[m][j2];
                d += __shfl_xor(d, 1); d += __shfl_xor(d, 2);
                d += __shfl_xor(d, 4); d += __shfl_xor(d, 8);
                if (fr == 0) {
                    const int nn = n0 + wr + m * 16 + ks * 4 + j2;
                    atomicAdd((float*)&auxf[(long)z * N_DIM + nn], d);
                }
            }
    }
    if (QGS) {
#pragma unroll
        for (int nf = 0; nf < 4; ++nf) {
            float d = qsum[nf];
            d += __shfl_xor(d, 16);
            d += __shfl_xor(d, 32);
            if (ks == 0) {
                const int oo = o0 + wc + nf * 16 + fr;
                atomicAdd((float*)&auxf[((long)z << 9) + oo], d);
            }
        }
    }
}

// ---------------------------------------------------------------------------
// kv: kvp[nch][b][d][c] = sum_{n in 512-chunk nch} v0c[b][d][n] * khat[b][c][n]
// ---------------------------------------------------------------------------
__global__ __launch_bounds__(256, 3) void kv_mfma(
    const ushort_t* __restrict__ v0c, const ushort_t* __restrict__ khat,
    float* __restrict__ kvp)
{
    __shared__ ushort_t Als[2][128 * 32];
    __shared__ ushort_t Bls[2][128 * 32];
    const int tid = threadIdx.x;
    const int L = blockIdx.x;
    const int gpx = (gridDim.x >> 3) >> 2;
    const int xcd = L & 7;
    const int j = L >> 3;
    const int xtile = j & 3;
    const int g = xcd * gpx + (j >> 2);
    const int ytile = g & 3;
    const int z = g >> 2;
    const int c0 = xtile * 128, d0 = ytile * 128;
    const int b = z >> 3, nch = z & 7;

    const int w = tid >> 6, l = tid & 63;
    const int lr = l >> 2, lg = l & 3;
    const int rA0 = w * 32 + lr, rA1 = w * 32 + 16 + lr;
    const int gA0 = lg ^ ((rA0 >> 1) & 3), gA1 = lg ^ ((rA1 >> 1) & 3);
    const ushort_t* Ab = v0c + (long)b * CN_ + nch * 512;
    const ushort_t* Bb = khat + (long)b * CN_ + nch * 512;
    const ushort_t* ap0 = Ab + (long)(d0 + rA0) * N_DIM + gA0 * 8;
    const ushort_t* ap1 = Ab + (long)(d0 + rA1) * N_DIM + gA1 * 8;
    const ushort_t* bp0 = Bb + (long)(c0 + rA0) * N_DIM + gA0 * 8;
    const ushort_t* bp1 = Bb + (long)(c0 + rA1) * N_DIM + gA1 * 8;
    const int la0 = (w * 32) * 32, la1 = (w * 32 + 16) * 32;

    const int wr = (w >> 1) * 64, wc = (w & 1) * 64;
    const int fr = l & 15, ks = l >> 4;
    const int rsw = (ks ^ ((fr >> 1) & 3)) << 3;

    f32x4 acc[4][4];
#pragma unroll
    for (int m = 0; m < 4; ++m)
#pragma unroll
        for (int nf = 0; nf < 4; ++nf) acc[m][nf] = f32x4{0.f, 0.f, 0.f, 0.f};

    KLOOP(512);

    float* KV = kvp + ((long)(nch * 4 + b)) * 262144;
#pragma unroll
    for (int m = 0; m < 4; ++m)
#pragma unroll
        for (int nf = 0; nf < 4; ++nf) {
            const int cc = c0 + wc + nf * 16 + fr;
#pragma unroll
            for (int j2 = 0; j2 < 4; ++j2) {
                const int dd = d0 + wr + m * 16 + ks * 4 + j2;
                KV[(long)dd * 512 + cc] = acc[m][nf][j2];
            }
        }
}

// kvT[i] = f2b( (1/sqrt(512)) * sum_nch kvp[nch][i] )
__global__ __launch_bounds__(256) void cvt_scale8(
    const float* __restrict__ kvp, ushort_t* __restrict__ out)
{
    const float s = 0.044194173824159216f;
    const long i = ((long)blockIdx.x * 256 + threadIdx.x) * 4;
    const int b = (int)(i >> 18);
    const long j = i & 262143;
    float4 a = make_float4(0.f, 0.f, 0.f, 0.f);
#pragma unroll
    for (int nch = 0; nch < 8; ++nch) {
        float4 v = *(const float4*)&kvp[((long)(nch * 4 + b)) * 262144 + j];
        a.x += v.x; a.y += v.y; a.z += v.z; a.w += v.w;
    }
    union { ushort_t sh[4]; uint2 u; } p;
    p.sh[0] = f2b(a.x * s); p.sh[1] = f2b(a.y * s);
    p.sh[2] = f2b(a.z * s); p.sh[3] = f2b(a.w * s);
    *(uint2*)&out[i] = p.u;
}

// ---------------------------------------------------------------------------
// fused Wphi + ybar, INTERLEAVED, counted vmcnt (8 loads/tile in flight)
// ---------------------------------------------------------------------------
__global__ __launch_bounds__(256, 2) void ybar_gemm(
    const ushort_t* __restrict__ q12, const ushort_t* __restrict__ kvT,
    const ushort_t* __restrict__ xT12, const ushort_t* __restrict__ Wphi_b,
    const float* __restrict__ den12, ushort_t* __restrict__ y12)
{
    __shared__ ushort_t Als[2][128 * 32];
    __shared__ ushort_t Bls[2][128 * 32];
    __shared__ ushort_t Cls[2][128 * 32];
    __shared__ ushort_t Dls[2][128 * 32];
    const int tid = threadIdx.x;
    const int L = blockIdx.x;
    const int gpx = (gridDim.x >> 3) >> 2;
    const int xcd = L & 7;
    const int j = L >> 3;
    const int xtile = j & 3;
    const int g = xcd * gpx + (j >> 2);
    const int ytile = g & 31;
    const int mm = g >> 5;
    const int o0 = xtile * 128, n0 = ytile * 128;

    const int w = tid >> 6, l = tid & 63;
    const int lr = l >> 2, lg = l & 3;
    const int rA0 = w * 32 + lr, rA1 = w * 32 + 16 + lr;
    const int gA0 = lg ^ ((rA0 >> 1) & 3), gA1 = lg ^ ((rA1 >> 1) & 3);
    const long aoff0 = (long)(n0 + rA0) * 512 + gA0 * 8;
    const long aoff1 = (long)(n0 + rA1) * 512 + gA1 * 8;
    const long boff0 = (long)(o0 + rA0) * 512 + gA0 * 8;
    const long boff1 = (long)(o0 + rA1) * 512 + gA1 * 8;
    const int la0 = (w * 32) * 32, la1 = (w * 32 + 16) * 32;

    const int wr = (w >> 1) * 64, wc = (w & 1) * 64;
    const int fr = l & 15, ks = l >> 4;
    const int rsw = (ks ^ ((fr >> 1) & 3)) << 3;

    const ushort_t* pa0 = xT12 + (long)mm * CN_ + aoff0;
    const ushort_t* pa1 = xT12 + (long)mm * CN_ + aoff1;
    const ushort_t* pb0 = Wphi_b + boff0;
    const ushort_t* pb1 = Wphi_b + boff1;
    const ushort_t* qa0 = q12 + (long)mm * CN_ + aoff0;
    const ushort_t* qa1 = q12 + (long)mm * CN_ + aoff1;
    const ushort_t* kb0 = kvT + (long)(mm & 3) * 262144 + boff0;
    const ushort_t* kb1 = kvT + (long)(mm & 3) * 262144 + boff1;

    f32x4 accP[4][4], accQ[4][4];
#pragma unroll
    for (int m = 0; m < 4; ++m)
#pragma unroll
        for (int nf = 0; nf < 4; ++nf) {
            accP[m][nf] = f32x4{0.f, 0.f, 0.f, 0.f};
            accQ[m][nf] = f32x4{0.f, 0.f, 0.f, 0.f};
        }

#define STAGE2(q, koff) { \
    GLOAD(pa0 + (koff), &Als[q][la0]); GLOAD(pa1 + (koff), &Als[q][la1]); \
    GLOAD(pb0 + (koff), &Bls[q][la0]); GLOAD(pb1 + (koff), &Bls[q][la1]); \
    GLOAD(qa0 + (koff), &Cls[q][la0]); GLOAD(qa1 + (koff), &Cls[q][la1]); \
    GLOAD(kb0 + (koff), &Dls[q][la0]); GLOAD(kb1 + (koff), &Dls[q][la1]); }

#define COMPUTE2(q) { \
    bf16x8 af[4], bfv[4], cf[4], df[4]; \
    _Pragma("unroll") for (int m_ = 0; m_ < 4; ++m_) { \
        af[m_] = *(const bf16x8*)&Als[q][(wr + m_ * 16 + fr) * 32 + rsw]; \
        cf[m_] = *(const bf16x8*)&Cls[q][(wr + m_ * 16 + fr) * 32 + rsw]; } \
    _Pragma("unroll") for (int nf_ = 0; nf_ < 4; ++nf_) { \
        bfv[nf_] = *(const bf16x8*)&Bls[q][(wc + nf_ * 16 + fr) * 32 + rsw]; \
        df[nf_] = *(const bf16x8*)&Dls[q][(wc + nf_ * 16 + fr) * 32 + rsw]; } \
    _Pragma("unroll") for (int m_ = 0; m_ < 4; ++m_) \
        _Pragma("unroll") for (int nf_ = 0; nf_ < 4; ++nf_) { \
            accP[m_][nf_] = __builtin_amdgcn_mfma_f32_16x16x32_bf16( \
                af[m_], bfv[nf_], accP[m_][nf_], 0, 0, 0); \
            accQ[m_][nf_] = __builtin_amdgcn_mfma_f32_16x16x32_bf16( \
                cf[m_], df[nf_], accQ[m_][nf_], 0, 0, 0); } }

    STAGE2(0, 0);
    STAGE2(1, 32);
    int s_ = 0;
    while (true) {
        if (s_ + 1 < 16) { WAITV8 } else { WAITV0 }
        SBAR;
        COMPUTE2(s_ & 1);
        SBAR;
        if (s_ + 2 < 16) STAGE2(s_ & 1, (s_ + 2) * 32);
        ++s_;
        if (s_ >= 16) break;
    }
#undef STAGE2
#undef COMPUTE2

    const float* D = den12 + (long)mm * N_DIM;
    ushort_t* Y = y12 + (long)mm * CN_;
#pragma unroll
    for (int m = 0; m < 4; ++m) {
        float zr[4];
#pragma unroll
        for (int j2 = 0; j2 < 4; ++j2)
            zr[j2] = 1.f / (D[n0 + wr + m * 16 + ks * 4 + j2] + 1e-6f);
#pragma unroll
        for (int nf = 0; nf < 4; ++nf) {
            const int oo = o0 + wc + nf * 16 + fr;
#pragma unroll
            for (int j2 = 0; j2 < 4; ++j2) {
                const int nn = n0 + wr + m * 16 + ks * 4 + j2;
                Y[(long)nn * 512 + oo] = f2b(accQ[m][nf][j2] * zr[j2] * accP[m][nf][j2]);
            }
        }
    }
}

// ybar stage B: ybar[i] = (1/12) sum_mm y12[mm][i]
__global__ __launch_bounds__(256) void ybar_reduce(
    const ushort_t* __restrict__ y12, float* __restrict__ ybar)
{
    const long i = ((long)blockIdx.x * 256 + threadIdx.x) * 8;
    float s[8] = {0.f, 0.f, 0.f, 0.f, 0.f, 0.f, 0.f, 0.f};
    for (int mm = 0; mm < 12; ++mm) {
        uint4 u = *(const uint4*)&y12[(long)mm * CN_ + i];
        const ushort_t* us = (const ushort_t*)&u;
#pragma unroll
        for (int j = 0; j < 8; ++j) s[j] += b2f(us[j]);
    }
#pragma unroll
    for (int j = 0; j < 8; ++j) s[j] *= (1.f / 12.f);
    *(float4*)&ybar[i] = make_float4(s[0], s[1], s[2], s[3]);
    *(float4*)&ybar[i + 4] = make_float4(s[4], s[5], s[6], s[7]);
}

// bf16 [z][4096][512] -> bf16 [z][512][4096]; ALPHA: out *= alpha[z][n],
// and ksum[z][c] += sum_n t[n][c]*alpha[n] (atomicAdd; pre-zeroed).
template<int ALPHA>
__global__ __launch_bounds__(256) void transpose_b2b(
    const ushort_t* __restrict__ in, ushort_t* __restrict__ out,
    const float* __restrict__ alpha, float* __restrict__ ksum)
{
    __shared__ ushort_t t[64][72];
    const int tid = threadIdx.x;
    const int n0 = blockIdx.x * 64, c0 = blockIdx.y * 64, z = blockIdx.z;
    const ushort_t* I = in + (long)z * CN_;
    ushort_t* O = out + (long)z * CN_;
    const int r = tid >> 2, s8 = (tid & 3) * 16;
    uint4 u0 = *(const uint4*)&I[(long)(n0 + r) * 512 + c0 + s8];
    uint4 u1 = *(const uint4*)&I[(long)(n0 + r) * 512 + c0 + s8 + 8];
    *(uint4*)&t[r][s8] = u0;
    *(uint4*)&t[r][s8 + 8] = u1;
    __syncthreads();
    union { ushort_t sh[16]; uint4 u[2]; } p;
#pragma unroll
    for (int i = 0; i < 16; ++i) {
        ushort_t v = t[s8 + i][r];
        if (ALPHA) v = f2b(b2f(v) * alpha[(long)z * N_DIM + n0 + s8 + i]);
        p.sh[i] = v;
    }
    uint4* dst = (uint4*)&O[(long)(c0 + r) * N_DIM + n0 + s8];
    dst[0] = p.u[0]; dst[1] = p.u[1];
    if (ALPHA) {
        const int c = tid & 63, q = tid >> 6;
        float s = 0.f;
#pragma unroll
        for (int i = 0; i < 16; ++i) {
            const int n = q * 16 + i;
            s += b2f(t[n][c]) * alpha[(long)z * N_DIM + n0 + n];
        }
        atomicAdd(&ksum[((long)z << 9) + c0 + c], s);
    }
}

// all-weights fp32 -> bf16 in one dispatch
__global__ __launch_bounds__(256) void cvt_all(
    const float* __restrict__ s0, ushort_t* __restrict__ d0,
    const float* __restrict__ s1, ushort_t* __restrict__ d1,
    const float* __restrict__ s2, ushort_t* __restrict__ d2,
    const float* __restrict__ s3, ushort_t* __restrict__ d3,
    const float* __restrict__ s4, ushort_t* __restrict__ d4,
    const float* __restrict__ s5, ushort_t* __restrict__ d5)
{
    long i = ((long)blockIdx.x * 256 + threadIdx.x) * 4;
    const float* s; ushort_t* d; long off;
    if (i < 65536)        { s = s0; d = d0; off = i; }
    else if (i < 131072)  { s = s1; d = d1; off = i - 65536; }
    else if (i < 393216)  { s = s2; d = d2; off = i - 131072; }
    else if (i < 655360)  { s = s3; d = d3; off = i - 393216; }
    else if (i < 1703936) { s = s4; d = d4; off = i - 655360; }
    else                  { s = s5; d = d5; off = i - 1703936; }
    float4 v = *(const float4*)&s[off];
    union { ushort_t sh[4]; uint2 u; } p;
    p.sh[0] = f2b(v.x); p.sh[1] = f2b(v.y); p.sh[2] = f2b(v.z); p.sh[3] = f2b(v.w);
    *(uint2*)&d[off] = p.u;
}

// transpose fp32 [z][rows][cols] -> bf16 [z][cols][rows].  (R15-proven)
// PASSZ: for z>=4 also copy the raw fp32 tile to passout (nontemporal).
template<int PASSZ>
__global__ __launch_bounds__(256) void transpose_f2b(
    const float* __restrict__ in, ushort_t* __restrict__ out,
    int rows, int cols, long in_z, long out_z, float* __restrict__ passout)
{
    __shared__ float t[64][65];
    const int tid = threadIdx.x;
    const int n0 = blockIdx.x * 64, c0 = blockIdx.y * 64;
    const int z = blockIdx.z;
    const float* I = in + (long)z * in_z;
    ushort_t* Ot = out + (long)z * out_z;
    const int r = tid >> 2, s4 = (tid & 3) * 16;
    f32x4 raw[4];
#pragma unroll
    for (int i = 0; i < 16; i += 4) {
        f32x4 v = *(const f32x4*)&I[(long)(c0 + r) * cols + n0 + s4 + i];
        raw[i >> 2] = v;
        t[r][s4 + i] = v.x; t[r][s4 + i + 1] = v.y;
        t[r][s4 + i + 2] = v.z; t[r][s4 + i + 3] = v.w;
    }
    if (PASSZ && z >= 4) {
        float* P = passout + (long)z * in_z + (long)(c0 + r) * cols + n0 + s4;
#pragma unroll
        for (int i = 0; i < 4; ++i)
            __builtin_nontemporal_store(raw[i], (f32x4*)&P[i * 4]);
    }
    __syncthreads();
    union { ushort_t s[16]; uint4 u[2]; } pk;
#pragma unroll
    for (int i = 0; i < 16; ++i) pk.s[i] = f2b(t[s4 + i][r]);
    uint4* dst = (uint4*)&Ot[(long)(n0 + r) * rows + c0 + s4];
    dst[0] = pk.u[0]; dst[1] = pk.u[1];
}

// out[z][n] = scale * sum_c X[z][n][c] * w[(z&3)][c]
__global__ __launch_bounds__(256) void dot_rows(
    const ushort_t* __restrict__ X, const float* __restrict__ w,
    float* __restrict__ out, float scale)
{
    const int tid = threadIdx.x;
    const int rn = tid >> 2, cs = (tid & 3) * 128;
    const int z = blockIdx.y;
    const int n = blockIdx.x * 64 + rn;
    const ushort_t* row = X + (long)z * CN_ + (long)n * C_DIM;
    const float* wz = w + (long)(z & 3) * C_DIM;
    float s = 0.f;
    for (int i = 0; i < 128; i += 8) {
        uint4 u = *(const uint4*)&row[cs + i];
        const ushort_t* us = (const ushort_t*)&u;
#pragma unroll
        for (int k2 = 0; k2 < 8; ++k2) s += b2f(us[k2]) * wz[cs + i + k2];
    }
    s += __shfl_xor(s, 1); s += __shfl_xor(s, 2);
    if ((tid & 3) == 0) out[(long)z * N_DIM + n] = s * scale;
}

// alpha[b,n] = softmax_n(logits[b,:]) * N
__global__ __launch_bounds__(256) void softmax_alpha(
    const float* __restrict__ logits, float* __restrict__ alpha)
{
    int b = blockIdx.x, tid = threadIdx.x;
    const float* L = logits + (long)b * N_DIM;
    float* A = alpha + (long)b * N_DIM;
    float lv[16];
    float mx = -3.4e38f;
#pragma unroll
    for (int i = 0; i < 4; i++) {
        float4 v = *(const float4*)&L[tid * 4 + i * 1024];
        lv[4 * i + 0] = v.x; lv[4 * i + 1] = v.y; lv[4 * i + 2] = v.z; lv[4 * i + 3] = v.w;
        mx = fmaxf(mx, fmaxf(fmaxf(v.x, v.y), fmaxf(v.z, v.w)));
    }
    __shared__ float red[8];
    float m = mx;
#pragma unroll
    for (int off = 32; off; off >>= 1) m = fmaxf(m, __shfl_down(m, off, 64));
    int wid = tid >> 6, lane = tid & 63;
    if (lane == 0) red[wid] = m;
    __syncthreads();
    m = fmaxf(fmaxf(red[0], red[1]), fmaxf(red[2], red[3]));
    float e[16], s = 0.f;
#pragma unroll
    for (int i = 0; i < 16; i++) { e[i] = expf(lv[i] - m); s += e[i]; }
#pragma unroll
    for (int off = 32; off; off >>= 1) s += __shfl_down(s, off, 64);
    if (lane == 0) red[4 + wid] = s;
    __syncthreads();
    float S = red[4] + red[5] + red[6] + red[7];
    float sc = 4096.f / S;
#pragma unroll
    for (int i = 0; i < 4; i++)
        *(float4*)&A[tid * 4 + i * 1024] =
            make_float4(e[4 * i] * sc, e[4 * i + 1] * sc, e[4 * i + 2] * sc, e[4 * i + 3] * sc);
}

// row LayerNorm over c (512) per (z,n); IBF: bf16 input; OBF: bf16 output
template<int RELU, int OBF, int IBF>
__global__ __launch_bounds__(256) void ln_row(
    const void* __restrict__ inv, const float* __restrict__ g,
    const float* __restrict__ bt, void* __restrict__ outv)
{
    const int tid = threadIdx.x;
    const int r = tid >> 3, cs = (tid & 7) * 64;
    const long base = (((long)blockIdx.y * N_DIM) + blockIdx.x * 32 + r) * C_DIM + cs;
    float vv[64];
    float s = 0.f, s2 = 0.f;
    if (IBF) {
        const ushort_t* I = (const ushort_t*)inv + base;
#pragma unroll
        for (int i = 0; i < 8; ++i) {
            uint4 u = *(const uint4*)&I[i * 8];
            const ushort_t* us = (const ushort_t*)&u;
#pragma unroll
            for (int jj = 0; jj < 8; ++jj) {
                float f = b2f(us[jj]); vv[i * 8 + jj] = f; s += f; s2 += f * f;
            }
        }
    } else {
        const float* I = (const float*)inv + base;
#pragma unroll
        for (int i = 0; i < 16; ++i) {
            float4 v = *(const float4*)&I[i * 4];
            vv[i * 4] = v.x; vv[i * 4 + 1] = v.y; vv[i * 4 + 2] = v.z; vv[i * 4 + 3] = v.w;
            s += v.x + v.y + v.z + v.w;
            s2 += v.x * v.x + v.y * v.y + v.z * v.z + v.w * v.w;
        }
    }
#pragma unroll
    for (int off = 1; off < 8; off <<= 1) { s += __shfl_xor(s, off); s2 += __shfl_xor(s2, off); }
    const float mean = s * (1.f / 512.f);
    const float var = s2 * (1.f / 512.f) - mean * mean;
    const float rs = rsqrtf(var + 1e-6f);
#pragma unroll
    for (int i = 0; i < 64; i += 4) {
        float o[4];
#pragma unroll
        for (int jj = 0; jj < 4; ++jj) {
            float ov = (vv[i + jj] - mean) * rs * g[cs + i + jj] + bt[cs + i + jj];
            if (RELU) ov = fmaxf(ov, 0.f);
            o[jj] = ov;
        }
        if (OBF) {
            union { ushort_t s4[4]; uint2 u; } p;
            p.s4[0] = f2b(o[0]); p.s4[1] = f2b(o[1]); p.s4[2] = f2b(o[2]); p.s4[3] = f2b(o[3]);
            *(uint2*)&((ushort_t*)outv)[base + i] = p.u;
        } else {
            *(float4*)&((float*)outv)[base + i] = make_float4(o[0], o[1], o[2], o[3]);
        }
    }
}

// fused LN2 + relu + transpose: in bf16 [z][n][c] -> out fp32 [z][c][n]
// (final output: nontemporal stores)
__global__ __launch_bounds__(256) void ln_tr(
    const ushort_t* __restrict__ in, const float* __restrict__ g,
    const float* __restrict__ bt, float* __restrict__ out)
{
    __shared__ float t[32][513];
    const int tid = threadIdx.x;
    const int r = tid >> 3;
    const int lc = (tid & 7) * 8;
    const int z = blockIdx.y;
    const long n = (long)blockIdx.x * 32 + r;
    const ushort_t* I = in + ((long)z * N_DIM + n) * C_DIM;
    float vv[64];
    float s = 0.f, s2 = 0.f;
#pragma unroll
    for (int i = 0; i < 8; ++i) {
        const int c = i * 64 + lc;
        uint4 u = *(const uint4*)&I[c];
        const ushort_t* us = (const ushort_t*)&u;
#pragma unroll
        for (int jj = 0; jj < 8; ++jj) {
            float f = b2f(us[jj]); vv[i * 8 + jj] = f; s += f; s2 += f * f;
        }
    }
#pragma unroll
    for (int off = 1; off < 8; off <<= 1) { s += __shfl_xor(s, off); s2 += __shfl_xor(s2, off); }
    const float mean = s * (1.f / 512.f);
    const float var = s2 * (1.f / 512.f) - mean * mean;
    const float rs = rsqrtf(var + 1e-6f);
#pragma unroll
    for (int i = 0; i < 8; ++i) {
        const int c = i * 64 + lc;
#pragma unroll
        for (int jj = 0; jj < 8; ++jj) {
            float o = (vv[i * 8 + jj] - mean) * rs * g[c + jj] + bt[c + jj];
            t[r][c + jj] = fmaxf(o, 0.f);
        }
    }
    __syncthreads();
    float* O = out + (long)z * CN_ + (long)blockIdx.x * 32;
    for (int c = tid; c < 512; c += 256) {
        float* dst = O + (long)c * N_DIM;
#pragma unroll
        for (int i = 0; i < 32; i += 4) {
            f32x4 v = {t[i][c], t[i + 1][c], t[i + 2][c], t[i + 3][c]};
            __builtin_nontemporal_store(v, (f32x4*)&dst[i]);
        }
    }
}

extern "C" void kernel_launch(void* const* d_in, const int* in_sizes, int n_in,
                              void* d_out, int out_size, void* d_ws, size_t ws_size,
                              hipStream_t stream)
{
    const float* x     = (const float*)d_in[0];
    const float* Wq    = (const float*)d_in[1];
    const float* Wk    = (const float*)d_in[2];
    const float* Wv    = (const float*)d_in[3];
    const float* Wphi  = (const float*)d_in[4];
    const float* ln1_w = (const float*)d_in[5];
    const float* ln1_b = (const float*)d_in[6];
    const float* fc1_w = (const float*)d_in[7];
    const float* fc1_bias = (const float*)d_in[8];
    const float* fc2_w = (const float*)d_in[9];
    const float* fc2_bias = (const float*)d_in[10];
    const float* ln2_w = (const float*)d_in[11];
    const float* ln2_b = (const float*)d_in[12];
    float* out = (float*)d_out;

    float* ws = (float*)d_ws;
    const long CN = CN_;
    // region map (float units); lifetimes are stream-sequential:
    ushort_t* xTfirst = (ushort_t*)ws;                 // [0,2CN)  (tln later)
    ushort_t* tln     = (ushort_t*)ws;
    ushort_t* xT12 = (ushort_t*)(ws + 2 * CN);         // [2CN,8CN)
    ushort_t* hbuf4 = (ushort_t*)(ws + 2 * CN);        // stage3 reuse [2CN,6CN)
    ushort_t* q12   = (ushort_t*)(ws + 8 * CN);        // [8CN,14CN)
    ushort_t* y12   = (ushort_t*)(ws + 14 * CN);       // [14CN,20CN)
    ushort_t* k0b = (ushort_t*)(ws + 20 * CN);         // [20CN,22CN) stage1
    ushort_t* v0b = (ushort_t*)(ws + 22 * CN);         // [22CN,24CN) stage1
    ushort_t* pre_b = (ushort_t*)(ws + 20 * CN);       // stage3 reuse
    ushort_t* khat = (ushort_t*)(ws + 24 * CN);        // [24CN,26CN) stage1
    ushort_t* v0c  = (ushort_t*)(ws + 26 * CN);        // [26CN,28CN) stage1
    ushort_t* ubuf_b = (ushort_t*)(ws + 24 * CN);      // stage3 reuse
    float* ybar = ws + 32 * CN;                        // [32CN,33CN)
    float* kvp  = ws + 33 * CN;                        // 8388608 floats
    ushort_t* kvT = (ushort_t*)(ws + 33 * CN + 8388608);
    float* wb = ws + 33 * CN + 8388608 + 524288;
    ushort_t* Wk_b   = (ushort_t*)(wb);
    ushort_t* Wq_b   = (ushort_t*)(wb + 32768);
    ushort_t* Wv_b   = (ushort_t*)(wb + 65536);
    ushort_t* Wphi_b = (ushort_t*)(wb + 196608);
    ushort_t* fc1_b16 = (ushort_t*)(wb + 327680);
    ushort_t* fc2_b16 = (ushort_t*)(wb + 851968);
    float* Qg     = wb + 1376256;                      // 2048
    float* ksum   = wb + 1378304;                      // 2048
    float* logits = wb + 1380352;
    float* alpha  = wb + 1396736;
    float* den12  = wb + 1413120;                      // 49152

    dim3 blk(256);

    // all weights -> bf16; zero atomic accumulators
    cvt_all<<<2688, blk, 0, stream>>>(Wk, Wk_b, Wq, Wq_b, Wv, Wv_b,
                                      Wphi, Wphi_b, fc1_w, fc1_b16, fc2_w, fc2_b16);
    hipMemsetAsync(Qg, 0, 4096 * sizeof(float), stream);        // Qg + ksum
    hipMemsetAsync(den12, 0, 49152 * sizeof(float), stream);

    // all 16 batches transposed; z>=4 also writes raw x to out (passthrough, NT)
    transpose_f2b<1><<<dim3(64, 8, 16), blk, 0, stream>>>(
        x, xTfirst, 512, 4096, CN, CN, out);

    // stage 1: k0 (+Qg fused), v0, logits, alpha, khat (+ksum fused), v0c, kv
    mfma_gemm<EPI_PHI, true, true, false, true><<<512, blk, 0, stream>>>(
        Wk_b, xTfirst, k0b, nullptr, nullptr, Qg, 128, 512, 512, CN, CN, 0, 4, 32);
    mfma_gemm<EPI_NONE, false, true, false, false><<<512, blk, 0, stream>>>(
        Wv_b, xTfirst, v0b, nullptr, nullptr, nullptr, 512, 512, 512, CN, CN, 0, 4, 32);
    dot_rows<<<dim3(64, 4), blk, 0, stream>>>(k0b, Qg, logits, 1.f / 4096.f);
    softmax_alpha<<<4, blk, 0, stream>>>(logits, alpha);
    transpose_b2b<1><<<dim3(64, 8, 4), blk, 0, stream>>>(k0b, khat, alpha, ksum);
    transpose_b2b<0><<<dim3(64, 8, 4), blk, 0, stream>>>(v0b, v0c, nullptr, nullptr);
    kv_mfma<<<512, blk, 0, stream>>>(v0c, khat, kvp);
    cvt_scale8<<<1024, blk, 0, stream>>>(kvp, kvT);

    // stage 2: q (with fused den), interleaved phi+ybar, reduce
    mfma_gemm<EPI_PHI, true, true, true, false><<<1536, blk, 0, stream>>>(
        Wq_b, xT12, q12, ksum, nullptr, den12, 128, 512, 512, CN, CN, 0, 4, 32);
    ybar_gemm<<<1536, blk, 0, stream>>>(q12, kvT, xT12, Wphi_b, den12, y12);
    ybar_reduce<<<1024, blk, 0, stream>>>(y12, ybar);

    // stage 3: pre(bf16) = firstT + ybar*phiF; LN1; MLP; fused LN2+relu+transpose
    mfma_gemm<EPI_PRE, false, true, false, false><<<512, blk, 0, stream>>>(
        Wphi_b, xTfirst, pre_b, nullptr, xTfirst, ybar, 512, 512, 512, CN, CN, CN, 4, 32);
    ln_row<0, 1, 1><<<dim3(128, 4), blk, 0, stream>>>(pre_b, ln1_w, ln1_b, tln);
    mfma_gemm<EPI_RELU_BIAS, false, true, false, false><<<2048, blk, 0, stream>>>(
        fc1_b16, tln, hbuf4, fc1_bias, nullptr, nullptr,
        512, 2048, 512, CN, 8388608, 0, 16, 32);
    mfma_gemm<EPI_RES_BIAS, false, true, false, false><<<512, blk, 0, stream>>>(
        fc2_b16, hbuf4, ubuf_b, fc2_bias, tln, nullptr,
        2048, 512, 2048, 8388608, CN, CN, 4, 32);
    ln_tr<<<dim3(128, 4), blk, 0, stream>>>(ubuf_b, ln2_w, ln2_b, out);
}

// Round 19
// 453.025 us; speedup vs baseline: 1.2838x; 1.1833x over previous
//
#include <hip/hip_runtime.h>

#define N_DIM 4096
#define C_DIM 512
#define CN_ ((long)C_DIM * (long)N_DIM)   // 2,097,152

typedef unsigned short ushort_t;
typedef __attribute__((ext_vector_type(8))) short bf16x8;
typedef __attribute__((ext_vector_type(4))) float f32x4;

typedef const __attribute__((address_space(1))) unsigned int* gas_t;
typedef __attribute__((address_space(3))) unsigned int* las_t;
#define GLOAD(g, l) __builtin_amdgcn_global_load_lds((gas_t)(g), (las_t)(l), 16, 0, 0)

__device__ __forceinline__ ushort_t f2b(float f) {
    unsigned u = __builtin_bit_cast(unsigned, f);
    u += 0x7fffu + ((u >> 16) & 1u);
    return (ushort_t)(u >> 16);
}
__device__ __forceinline__ float b2f(ushort_t s) {
    return __builtin_bit_cast(float, (unsigned)s << 16);
}

enum { EPI_NONE = 0, EPI_PHI = 1, EPI_RELU_BIAS = 2, EPI_RES_BIAS = 3, EPI_PRE = 4 };

// raw barrier + scheduler fences (rule #18 / m152 discipline)
#define SBAR { __builtin_amdgcn_sched_barrier(0); __builtin_amdgcn_s_barrier(); __builtin_amdgcn_sched_barrier(0); }
#define WAITV0 { asm volatile("s_waitcnt vmcnt(0)" ::: "memory"); __builtin_amdgcn_sched_barrier(0); }
#define WAITV4 { asm volatile("s_waitcnt vmcnt(4)" ::: "memory"); __builtin_amdgcn_sched_barrier(0); }
#define WAITV8 { asm volatile("s_waitcnt vmcnt(8)" ::: "memory"); __builtin_amdgcn_sched_barrier(0); }

// Shared K-loop: 128x128 tile, 4 waves, BK=32, two LDS stage buffers.
// Counted vmcnt: next tile's 4 global_load_lds stay in flight across both
// barriers (T4); only the tail drains to 0.
#define STAGE(q, koff) { \
    GLOAD(ap0 + (koff), &Als[q][la0]); \
    GLOAD(ap1 + (koff), &Als[q][la1]); \
    GLOAD(bp0 + (koff), &Bls[q][la0]); \
    GLOAD(bp1 + (koff), &Bls[q][la1]); }

#define COMPUTE(q) { \
    bf16x8 af[4], bfv[4]; \
    _Pragma("unroll") for (int m_ = 0; m_ < 4; ++m_) \
        af[m_] = *(const bf16x8*)&Als[q][(wr + m_ * 16 + fr) * 32 + rsw]; \
    _Pragma("unroll") for (int nf_ = 0; nf_ < 4; ++nf_) \
        bfv[nf_] = *(const bf16x8*)&Bls[q][(wc + nf_ * 16 + fr) * 32 + rsw]; \
    _Pragma("unroll") for (int m_ = 0; m_ < 4; ++m_) \
        _Pragma("unroll") for (int nf_ = 0; nf_ < 4; ++nf_) \
            acc[m_][nf_] = __builtin_amdgcn_mfma_f32_16x16x32_bf16( \
                af[m_], bfv[nf_], acc[m_][nf_], 0, 0, 0); }

#define KLOOP(K_) { \
    const int S_ = (K_) / 32; \
    STAGE(0, 0); \
    if (S_ > 1) STAGE(1, 32); \
    int s_ = 0; \
    while (true) { \
        if (s_ + 1 < S_) { WAITV4 } else { WAITV0 } \
        SBAR; \
        COMPUTE(s_ & 1); \
        SBAR; \
        if (s_ + 2 < S_) STAGE(s_ & 1, (s_ + 2) * 32); \
        ++s_; \
        if (s_ >= S_) break; \
    } }

// ---------------------------------------------------------------------------
// bf16 MFMA GEMM: OUT[z][n][o] = epi( sum_k A[z][n][k] * W[o][k] )
// DEN: den[z][n] += sum_o v * ksum[(z&3)][o]  (ksum in bias, den in auxf)
// QGS: qg[z][o] += sum_n v  (qg in auxf; pre-zeroed)
// ---------------------------------------------------------------------------
template<int EPI, bool GROUPED, bool OBF, bool DEN, bool QGS>
__global__ __launch_bounds__(256, 3) void mfma_gemm(
    const ushort_t* __restrict__ Wb, const ushort_t* __restrict__ A,
    void* __restrict__ OUTV, const float* __restrict__ bias,
    const ushort_t* __restrict__ auxb, const float* __restrict__ auxf,
    int K, int O, int a_rstride, long a_zstride, long o_zstride, long auxb_zstride,
    int xt, int yt)
{
    __shared__ ushort_t Als[2][128 * 32];
    __shared__ ushort_t Bls[2][128 * 32];
    const int tid = threadIdx.x;

    const int L = blockIdx.x;
    const int gpx = (gridDim.x >> 3) / xt;
    const int xcd = L & 7;
    const int j = L >> 3;
    const int xtile = j % xt;
    const int g = xcd * gpx + j / xt;
    const int ytile = g % yt;
    const int z = g / yt;

    const int o0 = xtile * 128;
    const int n0 = ytile * 128;
    const ushort_t* Az = A + (long)z * a_zstride;
    const ushort_t* Wp = Wb;
    int kbase = 0, obase = o0;
    if (GROUPED) { int gg = o0 >> 7; Wp = Wb + (long)gg * (128 * 128); kbase = gg << 7; obase = 0; }

    const int w = tid >> 6, l = tid & 63;
    const int lr = l >> 2, lg = l & 3;
    const int rA0 = w * 32 + lr, rA1 = w * 32 + 16 + lr;
    const int gA0 = lg ^ ((rA0 >> 1) & 3), gA1 = lg ^ ((rA1 >> 1) & 3);
    const ushort_t* ap0 = Az + (long)(n0 + rA0) * a_rstride + kbase + gA0 * 8;
    const ushort_t* ap1 = Az + (long)(n0 + rA1) * a_rstride + kbase + gA1 * 8;
    const ushort_t* bp0 = Wp + (long)(obase + rA0) * K + gA0 * 8;
    const ushort_t* bp1 = Wp + (long)(obase + rA1) * K + gA1 * 8;
    const int la0 = (w * 32) * 32, la1 = (w * 32 + 16) * 32;

    const int wr = (w >> 1) * 64, wc = (w & 1) * 64;
    const int fr = l & 15, ks = l >> 4;
    const int rsw = (ks ^ ((fr >> 1) & 3)) << 3;

    f32x4 acc[4][4];
#pragma unroll
    for (int m = 0; m < 4; ++m)
#pragma unroll
        for (int nf = 0; nf < 4; ++nf) acc[m][nf] = f32x4{0.f, 0.f, 0.f, 0.f};

    KLOOP(K);

    float dsum[4][4];
    if (DEN) {
#pragma unroll
        for (int m = 0; m < 4; ++m)
#pragma unroll
            for (int j2 = 0; j2 < 4; ++j2) dsum[m][j2] = 0.f;
    }
    float qsum[4];
    if (QGS) {
#pragma unroll
        for (int nf = 0; nf < 4; ++nf) qsum[nf] = 0.f;
    }

#pragma unroll
    for (int m = 0; m < 4; ++m) {
#pragma unroll
        for (int nf = 0; nf < 4; ++nf) {
            const int oo = o0 + wc + nf * 16 + fr;
            float bval = 0.f;
            if (EPI == EPI_RELU_BIAS || EPI == EPI_RES_BIAS) bval = bias[oo];
            float kw = 0.f;
            if (DEN) kw = bias[((z & 3) << 9) + oo];
#pragma unroll
            for (int j2 = 0; j2 < 4; ++j2) {
                const int nn = n0 + wr + m * 16 + ks * 4 + j2;
                const long ridx = (long)nn * O + oo;
                float v = acc[m][nf][j2];
                if (EPI == EPI_PHI)            v = fmaxf(v, 0.f) + 1.f;
                else if (EPI == EPI_RELU_BIAS) v = fmaxf(v + bval, 0.f);
                else if (EPI == EPI_RES_BIAS)  v = v + bval + b2f(auxb[(long)z * auxb_zstride + ridx]);
                else if (EPI == EPI_PRE)       v = b2f(auxb[(long)z * auxb_zstride + ridx]) + auxf[ridx] * v;
                if (DEN) dsum[m][j2] += v * kw;
                if (QGS) qsum[nf] += v;
                if (OBF) ((ushort_t*)OUTV)[(long)z * o_zstride + ridx] = f2b(v);
                else     ((float*)OUTV)[(long)z * o_zstride + ridx] = v;
            }
        }
    }

    if (DEN) {
#pragma unroll
        for (int m = 0; m < 4; ++m)
#pragma unroll
            for (int j2 = 0; j2 < 4; ++j2) {
                float d = dsum[m][j2];
                d += __shfl_xor(d, 1); d += __shfl_xor(d, 2);
                d += __shfl_xor(d, 4); d += __shfl_xor(d, 8);
                if (fr == 0) {
                    const int nn = n0 + wr + m * 16 + ks * 4 + j2;
                    atomicAdd((float*)&auxf[(long)z * N_DIM + nn], d);
                }
            }
    }
    if (QGS) {
#pragma unroll
        for (int nf = 0; nf < 4; ++nf) {
            float d = qsum[nf];
            d += __shfl_xor(d, 16);
            d += __shfl_xor(d, 32);
            if (ks == 0) {
                const int oo = o0 + wc + nf * 16 + fr;
                atomicAdd((float*)&auxf[((long)z << 9) + oo], d);
            }
        }
    }
}

// ---------------------------------------------------------------------------
// kv: kvp[nch][b][d][c] = sum_{n in 512-chunk nch} v0c[b][d][n] * khat[b][c][n]
// ---------------------------------------------------------------------------
__global__ __launch_bounds__(256, 3) void kv_mfma(
    const ushort_t* __restrict__ v0c, const ushort_t* __restrict__ khat,
    float* __restrict__ kvp)
{
    __shared__ ushort_t Als[2][128 * 32];
    __shared__ ushort_t Bls[2][128 * 32];
    const int tid = threadIdx.x;
    const int L = blockIdx.x;
    const int gpx = (gridDim.x >> 3) >> 2;
    const int xcd = L & 7;
    const int j = L >> 3;
    const int xtile = j & 3;
    const int g = xcd * gpx + (j >> 2);
    const int ytile = g & 3;
    const int z = g >> 2;
    const int c0 = xtile * 128, d0 = ytile * 128;
    const int b = z >> 3, nch = z & 7;

    const int w = tid >> 6, l = tid & 63;
    const int lr = l >> 2, lg = l & 3;
    const int rA0 = w * 32 + lr, rA1 = w * 32 + 16 + lr;
    const int gA0 = lg ^ ((rA0 >> 1) & 3), gA1 = lg ^ ((rA1 >> 1) & 3);
    const ushort_t* Ab = v0c + (long)b * CN_ + nch * 512;
    const ushort_t* Bb = khat + (long)b * CN_ + nch * 512;
    const ushort_t* ap0 = Ab + (long)(d0 + rA0) * N_DIM + gA0 * 8;
    const ushort_t* ap1 = Ab + (long)(d0 + rA1) * N_DIM + gA1 * 8;
    const ushort_t* bp0 = Bb + (long)(c0 + rA0) * N_DIM + gA0 * 8;
    const ushort_t* bp1 = Bb + (long)(c0 + rA1) * N_DIM + gA1 * 8;
    const int la0 = (w * 32) * 32, la1 = (w * 32 + 16) * 32;

    const int wr = (w >> 1) * 64, wc = (w & 1) * 64;
    const int fr = l & 15, ks = l >> 4;
    const int rsw = (ks ^ ((fr >> 1) & 3)) << 3;

    f32x4 acc[4][4];
#pragma unroll
    for (int m = 0; m < 4; ++m)
#pragma unroll
        for (int nf = 0; nf < 4; ++nf) acc[m][nf] = f32x4{0.f, 0.f, 0.f, 0.f};

    KLOOP(512);

    float* KV = kvp + ((long)(nch * 4 + b)) * 262144;
#pragma unroll
    for (int m = 0; m < 4; ++m)
#pragma unroll
        for (int nf = 0; nf < 4; ++nf) {
            const int cc = c0 + wc + nf * 16 + fr;
#pragma unroll
            for (int j2 = 0; j2 < 4; ++j2) {
                const int dd = d0 + wr + m * 16 + ks * 4 + j2;
                KV[(long)dd * 512 + cc] = acc[m][nf][j2];
            }
        }
}

// kvT[i] = f2b( (1/sqrt(512)) * sum_nch kvp[nch][i] )
__global__ __launch_bounds__(256) void cvt_scale8(
    const float* __restrict__ kvp, ushort_t* __restrict__ out)
{
    const float s = 0.044194173824159216f;
    const long i = ((long)blockIdx.x * 256 + threadIdx.x) * 4;
    const int b = (int)(i >> 18);
    const long j = i & 262143;
    float4 a = make_float4(0.f, 0.f, 0.f, 0.f);
#pragma unroll
    for (int nch = 0; nch < 8; ++nch) {
        float4 v = *(const float4*)&kvp[((long)(nch * 4 + b)) * 262144 + j];
        a.x += v.x; a.y += v.y; a.z += v.z; a.w += v.w;
    }
    union { ushort_t sh[4]; uint2 u; } p;
    p.sh[0] = f2b(a.x * s); p.sh[1] = f2b(a.y * s);
    p.sh[2] = f2b(a.z * s); p.sh[3] = f2b(a.w * s);
    *(uint2*)&out[i] = p.u;
}

// ---------------------------------------------------------------------------
// fused Wphi + ybar, INTERLEAVED, counted vmcnt (8 loads/tile in flight)
// ---------------------------------------------------------------------------
__global__ __launch_bounds__(256, 2) void ybar_gemm(
    const ushort_t* __restrict__ q12, const ushort_t* __restrict__ kvT,
    const ushort_t* __restrict__ xT12, const ushort_t* __restrict__ Wphi_b,
    const float* __restrict__ den12, ushort_t* __restrict__ y12)
{
    __shared__ ushort_t Als[2][128 * 32];
    __shared__ ushort_t Bls[2][128 * 32];
    __shared__ ushort_t Cls[2][128 * 32];
    __shared__ ushort_t Dls[2][128 * 32];
    const int tid = threadIdx.x;
    const int L = blockIdx.x;
    const int gpx = (gridDim.x >> 3) >> 2;
    const int xcd = L & 7;
    const int j = L >> 3;
    const int xtile = j & 3;
    const int g = xcd * gpx + (j >> 2);
    const int ytile = g & 31;
    const int mm = g >> 5;
    const int o0 = xtile * 128, n0 = ytile * 128;

    const int w = tid >> 6, l = tid & 63;
    const int lr = l >> 2, lg = l & 3;
    const int rA0 = w * 32 + lr, rA1 = w * 32 + 16 + lr;
    const int gA0 = lg ^ ((rA0 >> 1) & 3), gA1 = lg ^ ((rA1 >> 1) & 3);
    const long aoff0 = (long)(n0 + rA0) * 512 + gA0 * 8;
    const long aoff1 = (long)(n0 + rA1) * 512 + gA1 * 8;
    const long boff0 = (long)(o0 + rA0) * 512 + gA0 * 8;
    const long boff1 = (long)(o0 + rA1) * 512 + gA1 * 8;
    const int la0 = (w * 32) * 32, la1 = (w * 32 + 16) * 32;

    const int wr = (w >> 1) * 64, wc = (w & 1) * 64;
    const int fr = l & 15, ks = l >> 4;
    const int rsw = (ks ^ ((fr >> 1) & 3)) << 3;

    const ushort_t* pa0 = xT12 + (long)mm * CN_ + aoff0;
    const ushort_t* pa1 = xT12 + (long)mm * CN_ + aoff1;
    const ushort_t* pb0 = Wphi_b + boff0;
    const ushort_t* pb1 = Wphi_b + boff1;
    const ushort_t* qa0 = q12 + (long)mm * CN_ + aoff0;
    const ushort_t* qa1 = q12 + (long)mm * CN_ + aoff1;
    const ushort_t* kb0 = kvT + (long)(mm & 3) * 262144 + boff0;
    const ushort_t* kb1 = kvT + (long)(mm & 3) * 262144 + boff1;

    f32x4 accP[4][4], accQ[4][4];
#pragma unroll
    for (int m = 0; m < 4; ++m)
#pragma unroll
        for (int nf = 0; nf < 4; ++nf) {
            accP[m][nf] = f32x4{0.f, 0.f, 0.f, 0.f};
            accQ[m][nf] = f32x4{0.f, 0.f, 0.f, 0.f};
        }

#define STAGE2(q, koff) { \
    GLOAD(pa0 + (koff), &Als[q][la0]); GLOAD(pa1 + (koff), &Als[q][la1]); \
    GLOAD(pb0 + (koff), &Bls[q][la0]); GLOAD(pb1 + (koff), &Bls[q][la1]); \
    GLOAD(qa0 + (koff), &Cls[q][la0]); GLOAD(qa1 + (koff), &Cls[q][la1]); \
    GLOAD(kb0 + (koff), &Dls[q][la0]); GLOAD(kb1 + (koff), &Dls[q][la1]); }

#define COMPUTE2(q) { \
    bf16x8 af[4], bfv[4], cf[4], df[4]; \
    _Pragma("unroll") for (int m_ = 0; m_ < 4; ++m_) { \
        af[m_] = *(const bf16x8*)&Als[q][(wr + m_ * 16 + fr) * 32 + rsw]; \
        cf[m_] = *(const bf16x8*)&Cls[q][(wr + m_ * 16 + fr) * 32 + rsw]; } \
    _Pragma("unroll") for (int nf_ = 0; nf_ < 4; ++nf_) { \
        bfv[nf_] = *(const bf16x8*)&Bls[q][(wc + nf_ * 16 + fr) * 32 + rsw]; \
        df[nf_] = *(const bf16x8*)&Dls[q][(wc + nf_ * 16 + fr) * 32 + rsw]; } \
    _Pragma("unroll") for (int m_ = 0; m_ < 4; ++m_) \
        _Pragma("unroll") for (int nf_ = 0; nf_ < 4; ++nf_) { \
            accP[m_][nf_] = __builtin_amdgcn_mfma_f32_16x16x32_bf16( \
                af[m_], bfv[nf_], accP[m_][nf_], 0, 0, 0); \
            accQ[m_][nf_] = __builtin_amdgcn_mfma_f32_16x16x32_bf16( \
                cf[m_], df[nf_], accQ[m_][nf_], 0, 0, 0); } }

    STAGE2(0, 0);
    STAGE2(1, 32);
    int s_ = 0;
    while (true) {
        if (s_ + 1 < 16) { WAITV8 } else { WAITV0 }
        SBAR;
        COMPUTE2(s_ & 1);
        SBAR;
        if (s_ + 2 < 16) STAGE2(s_ & 1, (s_ + 2) * 32);
        ++s_;
        if (s_ >= 16) break;
    }
#undef STAGE2
#undef COMPUTE2

    const float* D = den12 + (long)mm * N_DIM;
    ushort_t* Y = y12 + (long)mm * CN_;
#pragma unroll
    for (int m = 0; m < 4; ++m) {
        float zr[4];
#pragma unroll
        for (int j2 = 0; j2 < 4; ++j2)
            zr[j2] = 1.f / (D[n0 + wr + m * 16 + ks * 4 + j2] + 1e-6f);
#pragma unroll
        for (int nf = 0; nf < 4; ++nf) {
            const int oo = o0 + wc + nf * 16 + fr;
#pragma unroll
            for (int j2 = 0; j2 < 4; ++j2) {
                const int nn = n0 + wr + m * 16 + ks * 4 + j2;
                Y[(long)nn * 512 + oo] = f2b(accQ[m][nf][j2] * zr[j2] * accP[m][nf][j2]);
            }
        }
    }
}

// ybar stage B: ybar[i] = (1/12) sum_mm y12[mm][i]
__global__ __launch_bounds__(256) void ybar_reduce(
    const ushort_t* __restrict__ y12, float* __restrict__ ybar)
{
    const long i = ((long)blockIdx.x * 256 + threadIdx.x) * 8;
    float s[8] = {0.f, 0.f, 0.f, 0.f, 0.f, 0.f, 0.f, 0.f};
    for (int mm = 0; mm < 12; ++mm) {
        uint4 u = *(const uint4*)&y12[(long)mm * CN_ + i];
        const ushort_t* us = (const ushort_t*)&u;
#pragma unroll
        for (int j = 0; j < 8; ++j) s[j] += b2f(us[j]);
    }
#pragma unroll
    for (int j = 0; j < 8; ++j) s[j] *= (1.f / 12.f);
    *(float4*)&ybar[i] = make_float4(s[0], s[1], s[2], s[3]);
    *(float4*)&ybar[i + 4] = make_float4(s[4], s[5], s[6], s[7]);
}

// bf16 [z][4096][512] -> bf16 [z][512][4096]; ALPHA: out *= alpha[z][n],
// and ksum[z][c] += sum_n t[n][c]*alpha[n] (atomicAdd; pre-zeroed).
template<int ALPHA>
__global__ __launch_bounds__(256) void transpose_b2b(
    const ushort_t* __restrict__ in, ushort_t* __restrict__ out,
    const float* __restrict__ alpha, float* __restrict__ ksum)
{
    __shared__ ushort_t t[64][72];
    const int tid = threadIdx.x;
    const int n0 = blockIdx.x * 64, c0 = blockIdx.y * 64, z = blockIdx.z;
    const ushort_t* I = in + (long)z * CN_;
    ushort_t* O = out + (long)z * CN_;
    const int r = tid >> 2, s8 = (tid & 3) * 16;
    uint4 u0 = *(const uint4*)&I[(long)(n0 + r) * 512 + c0 + s8];
    uint4 u1 = *(const uint4*)&I[(long)(n0 + r) * 512 + c0 + s8 + 8];
    *(uint4*)&t[r][s8] = u0;
    *(uint4*)&t[r][s8 + 8] = u1;
    __syncthreads();
    union { ushort_t sh[16]; uint4 u[2]; } p;
#pragma unroll
    for (int i = 0; i < 16; ++i) {
        ushort_t v = t[s8 + i][r];
        if (ALPHA) v = f2b(b2f(v) * alpha[(long)z * N_DIM + n0 + s8 + i]);
        p.sh[i] = v;
    }
    uint4* dst = (uint4*)&O[(long)(c0 + r) * N_DIM + n0 + s8];
    dst[0] = p.u[0]; dst[1] = p.u[1];
    if (ALPHA) {
        const int c = tid & 63, q = tid >> 6;
        float s = 0.f;
#pragma unroll
        for (int i = 0; i < 16; ++i) {
            const int n = q * 16 + i;
            s += b2f(t[n][c]) * alpha[(long)z * N_DIM + n0 + n];
        }
        atomicAdd(&ksum[((long)z << 9) + c0 + c], s);
    }
}

// all-weights fp32 -> bf16 in one dispatch
__global__ __launch_bounds__(256) void cvt_all(
    const float* __restrict__ s0, ushort_t* __restrict__ d0,
    const float* __restrict__ s1, ushort_t* __restrict__ d1,
    const float* __restrict__ s2, ushort_t* __restrict__ d2,
    const float* __restrict__ s3, ushort_t* __restrict__ d3,
    const float* __restrict__ s4, ushort_t* __restrict__ d4,
    const float* __restrict__ s5, ushort_t* __restrict__ d5)
{
    long i = ((long)blockIdx.x * 256 + threadIdx.x) * 4;
    const float* s; ushort_t* d; long off;
    if (i < 65536)        { s = s0; d = d0; off = i; }
    else if (i < 131072)  { s = s1; d = d1; off = i - 65536; }
    else if (i < 393216)  { s = s2; d = d2; off = i - 131072; }
    else if (i < 655360)  { s = s3; d = d3; off = i - 393216; }
    else if (i < 1703936) { s = s4; d = d4; off = i - 655360; }
    else                  { s = s5; d = d5; off = i - 1703936; }
    float4 v = *(const float4*)&s[off];
    union { ushort_t sh[4]; uint2 u; } p;
    p.sh[0] = f2b(v.x); p.sh[1] = f2b(v.y); p.sh[2] = f2b(v.z); p.sh[3] = f2b(v.w);
    *(uint2*)&d[off] = p.u;
}

// transpose fp32 [z][rows][cols] -> bf16 [z][cols][rows].
// PASSZ: for z>=4 also copy the raw fp32 tile to passout.
template<int PASSZ>
__global__ __launch_bounds__(256) void transpose_f2b(
    const float* __restrict__ in, ushort_t* __restrict__ out,
    int rows, int cols, long in_z, long out_z, float* __restrict__ passout)
{
    __shared__ float t[64][65];
    const int tid = threadIdx.x;
    const int n0 = blockIdx.x * 64, c0 = blockIdx.y * 64;
    const int z = blockIdx.z;
    const float* I = in + (long)z * in_z;
    ushort_t* Ot = out + (long)z * out_z;
    const int r = tid >> 2, s4 = (tid & 3) * 16;
    float4 raw[4];
#pragma unroll
    for (int i = 0; i < 16; i += 4) {
        float4 v = *(const float4*)&I[(long)(c0 + r) * cols + n0 + s4 + i];
        raw[i >> 2] = v;
        t[r][s4 + i] = v.x; t[r][s4 + i + 1] = v.y;
        t[r][s4 + i + 2] = v.z; t[r][s4 + i + 3] = v.w;
    }
    if (PASSZ && z >= 4) {
        float* P = passout + (long)z * in_z + (long)(c0 + r) * cols + n0 + s4;
#pragma unroll
        for (int i = 0; i < 4; ++i) *(float4*)&P[i * 4] = raw[i];
    }
    __syncthreads();
    union { ushort_t s[16]; uint4 u[2]; } pk;
#pragma unroll
    for (int i = 0; i < 16; ++i) pk.s[i] = f2b(t[s4 + i][r]);
    uint4* dst = (uint4*)&Ot[(long)(n0 + r) * rows + c0 + s4];
    dst[0] = pk.u[0]; dst[1] = pk.u[1];
}

// out[z][n] = scale * sum_c X[z][n][c] * w[(z&3)][c]
__global__ __launch_bounds__(256) void dot_rows(
    const ushort_t* __restrict__ X, const float* __restrict__ w,
    float* __restrict__ out, float scale)
{
    const int tid = threadIdx.x;
    const int rn = tid >> 2, cs = (tid & 3) * 128;
    const int z = blockIdx.y;
    const int n = blockIdx.x * 64 + rn;
    const ushort_t* row = X + (long)z * CN_ + (long)n * C_DIM;
    const float* wz = w + (long)(z & 3) * C_DIM;
    float s = 0.f;
    for (int i = 0; i < 128; i += 8) {
        uint4 u = *(const uint4*)&row[cs + i];
        const ushort_t* us = (const ushort_t*)&u;
#pragma unroll
        for (int k2 = 0; k2 < 8; ++k2) s += b2f(us[k2]) * wz[cs + i + k2];
    }
    s += __shfl_xor(s, 1); s += __shfl_xor(s, 2);
    if ((tid & 3) == 0) out[(long)z * N_DIM + n] = s * scale;
}

// alpha[b,n] = softmax_n(logits[b,:]) * N
__global__ __launch_bounds__(256) void softmax_alpha(
    const float* __restrict__ logits, float* __restrict__ alpha)
{
    int b = blockIdx.x, tid = threadIdx.x;
    const float* L = logits + (long)b * N_DIM;
    float* A = alpha + (long)b * N_DIM;
    float lv[16];
    float mx = -3.4e38f;
#pragma unroll
    for (int i = 0; i < 4; i++) {
        float4 v = *(const float4*)&L[tid * 4 + i * 1024];
        lv[4 * i + 0] = v.x; lv[4 * i + 1] = v.y; lv[4 * i + 2] = v.z; lv[4 * i + 3] = v.w;
        mx = fmaxf(mx, fmaxf(fmaxf(v.x, v.y), fmaxf(v.z, v.w)));
    }
    __shared__ float red[8];
    float m = mx;
#pragma unroll
    for (int off = 32; off; off >>= 1) m = fmaxf(m, __shfl_down(m, off, 64));
    int wid = tid >> 6, lane = tid & 63;
    if (lane == 0) red[wid] = m;
    __syncthreads();
    m = fmaxf(fmaxf(red[0], red[1]), fmaxf(red[2], red[3]));
    float e[16], s = 0.f;
#pragma unroll
    for (int i = 0; i < 16; i++) { e[i] = expf(lv[i] - m); s += e[i]; }
#pragma unroll
    for (int off = 32; off; off >>= 1) s += __shfl_down(s, off, 64);
    if (lane == 0) red[4 + wid] = s;
    __syncthreads();
    float S = red[4] + red[5] + red[6] + red[7];
    float sc = 4096.f / S;
#pragma unroll
    for (int i = 0; i < 4; i++)
        *(float4*)&A[tid * 4 + i * 1024] =
            make_float4(e[4 * i] * sc, e[4 * i + 1] * sc, e[4 * i + 2] * sc, e[4 * i + 3] * sc);
}

// row LayerNorm over c (512) per (z,n); IBF: bf16 input; OBF: bf16 output
template<int RELU, int OBF, int IBF>
__global__ __launch_bounds__(256) void ln_row(
    const void* __restrict__ inv, const float* __restrict__ g,
    const float* __restrict__ bt, void* __restrict__ outv)
{
    const int tid = threadIdx.x;
    const int r = tid >> 3, cs = (tid & 7) * 64;
    const long base = (((long)blockIdx.y * N_DIM) + blockIdx.x * 32 + r) * C_DIM + cs;
    float vv[64];
    float s = 0.f, s2 = 0.f;
    if (IBF) {
        const ushort_t* I = (const ushort_t*)inv + base;
#pragma unroll
        for (int i = 0; i < 8; ++i) {
            uint4 u = *(const uint4*)&I[i * 8];
            const ushort_t* us = (const ushort_t*)&u;
#pragma unroll
            for (int jj = 0; jj < 8; ++jj) {
                float f = b2f(us[jj]); vv[i * 8 + jj] = f; s += f; s2 += f * f;
            }
        }
    } else {
        const float* I = (const float*)inv + base;
#pragma unroll
        for (int i = 0; i < 16; ++i) {
            float4 v = *(const float4*)&I[i * 4];
            vv[i * 4] = v.x; vv[i * 4 + 1] = v.y; vv[i * 4 + 2] = v.z; vv[i * 4 + 3] = v.w;
            s += v.x + v.y + v.z + v.w;
            s2 += v.x * v.x + v.y * v.y + v.z * v.z + v.w * v.w;
        }
    }
#pragma unroll
    for (int off = 1; off < 8; off <<= 1) { s += __shfl_xor(s, off); s2 += __shfl_xor(s2, off); }
    const float mean = s * (1.f / 512.f);
    const float var = s2 * (1.f / 512.f) - mean * mean;
    const float rs = rsqrtf(var + 1e-6f);
#pragma unroll
    for (int i = 0; i < 64; i += 4) {
        float o[4];
#pragma unroll
        for (int jj = 0; jj < 4; ++jj) {
            float ov = (vv[i + jj] - mean) * rs * g[cs + i + jj] + bt[cs + i + jj];
            if (RELU) ov = fmaxf(ov, 0.f);
            o[jj] = ov;
        }
        if (OBF) {
            union { ushort_t s4[4]; uint2 u; } p;
            p.s4[0] = f2b(o[0]); p.s4[1] = f2b(o[1]); p.s4[2] = f2b(o[2]); p.s4[3] = f2b(o[3]);
            *(uint2*)&((ushort_t*)outv)[base + i] = p.u;
        } else {
            *(float4*)&((float*)outv)[base + i] = make_float4(o[0], o[1], o[2], o[3]);
        }
    }
}

// fused LN2 + relu + transpose: in bf16 [z][n][c] -> out fp32 [z][c][n]
__global__ __launch_bounds__(256) void ln_tr(
    const ushort_t* __restrict__ in, const float* __restrict__ g,
    const float* __restrict__ bt, float* __restrict__ out)
{
    __shared__ float t[32][513];
    const int tid = threadIdx.x;
    const int r = tid >> 3;
    const int lc = (tid & 7) * 8;
    const int z = blockIdx.y;
    const long n = (long)blockIdx.x * 32 + r;
    const ushort_t* I = in + ((long)z * N_DIM + n) * C_DIM;
    float vv[64];
    float s = 0.f, s2 = 0.f;
#pragma unroll
    for (int i = 0; i < 8; ++i) {
        const int c = i * 64 + lc;
        uint4 u = *(const uint4*)&I[c];
        const ushort_t* us = (const ushort_t*)&u;
#pragma unroll
        for (int jj = 0; jj < 8; ++jj) {
            float f = b2f(us[jj]); vv[i * 8 + jj] = f; s += f; s2 += f * f;
        }
    }
#pragma unroll
    for (int off = 1; off < 8; off <<= 1) { s += __shfl_xor(s, off); s2 += __shfl_xor(s2, off); }
    const float mean = s * (1.f / 512.f);
    const float var = s2 * (1.f / 512.f) - mean * mean;
    const float rs = rsqrtf(var + 1e-6f);
#pragma unroll
    for (int i = 0; i < 8; ++i) {
        const int c = i * 64 + lc;
#pragma unroll
        for (int jj = 0; jj < 8; ++jj) {
            float o = (vv[i * 8 + jj] - mean) * rs * g[c + jj] + bt[c + jj];
            t[r][c + jj] = fmaxf(o, 0.f);
        }
    }
    __syncthreads();
    float* O = out + (long)z * CN_ + (long)blockIdx.x * 32;
    for (int c = tid; c < 512; c += 256) {
        float* dst = O + (long)c * N_DIM;
#pragma unroll
        for (int i = 0; i < 32; i += 4)
            *(float4*)&dst[i] = make_float4(t[i][c], t[i + 1][c], t[i + 2][c], t[i + 3][c]);
    }
}

extern "C" void kernel_launch(void* const* d_in, const int* in_sizes, int n_in,
                              void* d_out, int out_size, void* d_ws, size_t ws_size,
                              hipStream_t stream)
{
    const float* x     = (const float*)d_in[0];
    const float* Wq    = (const float*)d_in[1];
    const float* Wk    = (const float*)d_in[2];
    const float* Wv    = (const float*)d_in[3];
    const float* Wphi  = (const float*)d_in[4];
    const float* ln1_w = (const float*)d_in[5];
    const float* ln1_b = (const float*)d_in[6];
    const float* fc1_w = (const float*)d_in[7];
    const float* fc1_bias = (const float*)d_in[8];
    const float* fc2_w = (const float*)d_in[9];
    const float* fc2_bias = (const float*)d_in[10];
    const float* ln2_w = (const float*)d_in[11];
    const float* ln2_b = (const float*)d_in[12];
    float* out = (float*)d_out;

    float* ws = (float*)d_ws;
    const long CN = CN_;
    // region map (float units); lifetimes are stream-sequential:
    ushort_t* xTfirst = (ushort_t*)ws;                 // [0,2CN)  (tln later)
    ushort_t* tln     = (ushort_t*)ws;
    ushort_t* xT12 = (ushort_t*)(ws + 2 * CN);         // [2CN,8CN)
    ushort_t* hbuf4 = (ushort_t*)(ws + 2 * CN);        // stage3 reuse [2CN,6CN)
    ushort_t* q12   = (ushort_t*)(ws + 8 * CN);        // [8CN,14CN)
    ushort_t* y12   = (ushort_t*)(ws + 14 * CN);       // [14CN,20CN)
    ushort_t* k0b = (ushort_t*)(ws + 20 * CN);         // [20CN,22CN) stage1
    ushort_t* v0b = (ushort_t*)(ws + 22 * CN);         // [22CN,24CN) stage1
    ushort_t* pre_b = (ushort_t*)(ws + 20 * CN);       // stage3 reuse
    ushort_t* khat = (ushort_t*)(ws + 24 * CN);        // [24CN,26CN) stage1
    ushort_t* v0c  = (ushort_t*)(ws + 26 * CN);        // [26CN,28CN) stage1
    ushort_t* ubuf_b = (ushort_t*)(ws + 24 * CN);      // stage3 reuse
    float* ybar = ws + 32 * CN;                        // [32CN,33CN)
    float* kvp  = ws + 33 * CN;                        // 8388608 floats
    ushort_t* kvT = (ushort_t*)(ws + 33 * CN + 8388608);
    float* wb = ws + 33 * CN + 8388608 + 524288;
    ushort_t* Wk_b   = (ushort_t*)(wb);
    ushort_t* Wq_b   = (ushort_t*)(wb + 32768);
    ushort_t* Wv_b   = (ushort_t*)(wb + 65536);
    ushort_t* Wphi_b = (ushort_t*)(wb + 196608);
    ushort_t* fc1_b16 = (ushort_t*)(wb + 327680);
    ushort_t* fc2_b16 = (ushort_t*)(wb + 851968);
    float* Qg     = wb + 1376256;                      // 2048
    float* ksum   = wb + 1378304;                      // 2048
    float* logits = wb + 1380352;
    float* alpha  = wb + 1396736;
    float* den12  = wb + 1413120;                      // 49152

    dim3 blk(256);

    // all weights -> bf16; zero atomic accumulators
    cvt_all<<<2688, blk, 0, stream>>>(Wk, Wk_b, Wq, Wq_b, Wv, Wv_b,
                                      Wphi, Wphi_b, fc1_w, fc1_b16, fc2_w, fc2_b16);
    hipMemsetAsync(Qg, 0, 4096 * sizeof(float), stream);        // Qg + ksum
    hipMemsetAsync(den12, 0, 49152 * sizeof(float), stream);

    // all 16 batches transposed; z>=4 also writes raw x to out (passthrough)
    transpose_f2b<1><<<dim3(64, 8, 16), blk, 0, stream>>>(
        x, xTfirst, 512, 4096, CN, CN, out);

    // stage 1: k0 (+Qg fused), v0, logits, alpha, khat (+ksum fused), v0c, kv
    mfma_gemm<EPI_PHI, true, true, false, true><<<512, blk, 0, stream>>>(
        Wk_b, xTfirst, k0b, nullptr, nullptr, Qg, 128, 512, 512, CN, CN, 0, 4, 32);
    mfma_gemm<EPI_NONE, false, true, false, false><<<512, blk, 0, stream>>>(
        Wv_b, xTfirst, v0b, nullptr, nullptr, nullptr, 512, 512, 512, CN, CN, 0, 4, 32);
    dot_rows<<<dim3(64, 4), blk, 0, stream>>>(k0b, Qg, logits, 1.f / 4096.f);
    softmax_alpha<<<4, blk, 0, stream>>>(logits, alpha);
    transpose_b2b<1><<<dim3(64, 8, 4), blk, 0, stream>>>(k0b, khat, alpha, ksum);
    transpose_b2b<0><<<dim3(64, 8, 4), blk, 0, stream>>>(v0b, v0c, nullptr, nullptr);
    kv_mfma<<<512, blk, 0, stream>>>(v0c, khat, kvp);
    cvt_scale8<<<1024, blk, 0, stream>>>(kvp, kvT);

    // stage 2: q (with fused den), interleaved phi+ybar, reduce
    mfma_gemm<EPI_PHI, true, true, true, false><<<1536, blk, 0, stream>>>(
        Wq_b, xT12, q12, ksum, nullptr, den12, 128, 512, 512, CN, CN, 0, 4, 32);
    ybar_gemm<<<1536, blk, 0, stream>>>(q12, kvT, xT12, Wphi_b, den12, y12);
    ybar_reduce<<<1024, blk, 0, stream>>>(y12, ybar);

    // stage 3: pre(bf16) = firstT + ybar*phiF; LN1; MLP; fused LN2+relu+transpose
    mfma_gemm<EPI_PRE, false, true, false, false><<<512, blk, 0, stream>>>(
        Wphi_b, xTfirst, pre_b, nullptr, xTfirst, ybar, 512, 512, 512, CN, CN, CN, 4, 32);
    ln_row<0, 1, 1><<<dim3(128, 4), blk, 0, stream>>>(pre_b, ln1_w, ln1_b, tln);
    mfma_gemm<EPI_RELU_BIAS, false, true, false, false><<<2048, blk, 0, stream>>>(
        fc1_b16, tln, hbuf4, fc1_bias, nullptr, nullptr,
        512, 2048, 512, CN, 8388608, 0, 16, 32);
    mfma_gemm<EPI_RES_BIAS, false, true, false, false><<<512, blk, 0, stream>>>(
        fc2_b16, hbuf4, ubuf_b, fc2_bias, tln, nullptr,
        2048, 512, 2048, 8388608, CN, CN, 4, 32);
    ln_tr<<<dim3(128, 4), blk, 0, stream>>>(ubuf_b, ln2_w, ln2_b, out);
}

// Round 20
// 438.845 us; speedup vs baseline: 1.3253x; 1.0323x over previous
//
#include <hip/hip_runtime.h>

#define N_DIM 4096
#define C_DIM 512
#define CN_ ((long)C_DIM * (long)N_DIM)   // 2,097,152

typedef unsigned short ushort_t;
typedef __attribute__((ext_vector_type(8))) short bf16x8;
typedef __attribute__((ext_vector_type(4))) float f32x4;

typedef const __attribute__((address_space(1))) unsigned int* gas_t;
typedef __attribute__((address_space(3))) unsigned int* las_t;
#define GLOAD(g, l) __builtin_amdgcn_global_load_lds((gas_t)(g), (las_t)(l), 16, 0, 0)

__device__ __forceinline__ ushort_t f2b(float f) {
    unsigned u = __builtin_bit_cast(unsigned, f);
    u += 0x7fffu + ((u >> 16) & 1u);
    return (ushort_t)(u >> 16);
}
__device__ __forceinline__ float b2f(ushort_t s) {
    return __builtin_bit_cast(float, (unsigned)s << 16);
}

enum { EPI_NONE = 0, EPI_PHI = 1, EPI_RELU_BIAS = 2, EPI_RES_BIAS = 3, EPI_PRE = 4 };

// raw barrier + scheduler fences (rule #18 / m152 discipline)
#define SBAR { __builtin_amdgcn_sched_barrier(0); __builtin_amdgcn_s_barrier(); __builtin_amdgcn_sched_barrier(0); }
#define WAITV0 { asm volatile("s_waitcnt vmcnt(0)" ::: "memory"); __builtin_amdgcn_sched_barrier(0); }
#define WAITV4 { asm volatile("s_waitcnt vmcnt(4)" ::: "memory"); __builtin_amdgcn_sched_barrier(0); }
#define WAITV8 { asm volatile("s_waitcnt vmcnt(8)" ::: "memory"); __builtin_amdgcn_sched_barrier(0); }

// Shared K-loop: 128x128 tile, 4 waves, BK=32, two LDS stage buffers.
// Counted vmcnt: next tile's 4 global_load_lds stay in flight across both
// barriers (T4); only the tail drains to 0.
#define STAGE(q, koff) { \
    GLOAD(ap0 + (koff), &Als[q][la0]); \
    GLOAD(ap1 + (koff), &Als[q][la1]); \
    GLOAD(bp0 + (koff), &Bls[q][la0]); \
    GLOAD(bp1 + (koff), &Bls[q][la1]); }

#define COMPUTE(q) { \
    bf16x8 af[4], bfv[4]; \
    _Pragma("unroll") for (int m_ = 0; m_ < 4; ++m_) \
        af[m_] = *(const bf16x8*)&Als[q][(wr + m_ * 16 + fr) * 32 + rsw]; \
    _Pragma("unroll") for (int nf_ = 0; nf_ < 4; ++nf_) \
        bfv[nf_] = *(const bf16x8*)&Bls[q][(wc + nf_ * 16 + fr) * 32 + rsw]; \
    _Pragma("unroll") for (int m_ = 0; m_ < 4; ++m_) \
        _Pragma("unroll") for (int nf_ = 0; nf_ < 4; ++nf_) \
            acc[m_][nf_] = __builtin_amdgcn_mfma_f32_16x16x32_bf16( \
                af[m_], bfv[nf_], acc[m_][nf_], 0, 0, 0); }

#define KLOOP(K_) { \
    const int S_ = (K_) / 32; \
    STAGE(0, 0); \
    if (S_ > 1) STAGE(1, 32); \
    int s_ = 0; \
    while (true) { \
        if (s_ + 1 < S_) { WAITV4 } else { WAITV0 } \
        SBAR; \
        COMPUTE(s_ & 1); \
        SBAR; \
        if (s_ + 2 < S_) STAGE(s_ & 1, (s_ + 2) * 32); \
        ++s_; \
        if (s_ >= S_) break; \
    } }

// ---------------------------------------------------------------------------
// bf16 MFMA GEMM: OUT[z][n][o] = epi( sum_k A[z][n][k] * W[o][k] )
// DEN: den[z][n] += sum_o v * ksum[(z&3)][o]  (ksum in bias, den in auxf)
// QGS: qg[z][o] += sum_n v  (qg in auxf; pre-zeroed)
// ---------------------------------------------------------------------------
template<int EPI, bool GROUPED, bool OBF, bool DEN, bool QGS>
__global__ __launch_bounds__(256, 3) void mfma_gemm(
    const ushort_t* __restrict__ Wb, const ushort_t* __restrict__ A,
    void* __restrict__ OUTV, const float* __restrict__ bias,
    const ushort_t* __restrict__ auxb, const float* __restrict__ auxf,
    int K, int O, int a_rstride, long a_zstride, long o_zstride, long auxb_zstride,
    int xt, int yt)
{
    __shared__ ushort_t Als[2][128 * 32];
    __shared__ ushort_t Bls[2][128 * 32];
    const int tid = threadIdx.x;

    const int L = blockIdx.x;
    const int gpx = (gridDim.x >> 3) / xt;
    const int xcd = L & 7;
    const int j = L >> 3;
    const int xtile = j % xt;
    const int g = xcd * gpx + j / xt;
    const int ytile = g % yt;
    const int z = g / yt;

    const int o0 = xtile * 128;
    const int n0 = ytile * 128;
    const ushort_t* Az = A + (long)z * a_zstride;
    const ushort_t* Wp = Wb;
    int kbase = 0, obase = o0;
    if (GROUPED) { int gg = o0 >> 7; Wp = Wb + (long)gg * (128 * 128); kbase = gg << 7; obase = 0; }

    const int w = tid >> 6, l = tid & 63;
    const int lr = l >> 2, lg = l & 3;
    const int rA0 = w * 32 + lr, rA1 = w * 32 + 16 + lr;
    const int gA0 = lg ^ ((rA0 >> 1) & 3), gA1 = lg ^ ((rA1 >> 1) & 3);
    const ushort_t* ap0 = Az + (long)(n0 + rA0) * a_rstride + kbase + gA0 * 8;
    const ushort_t* ap1 = Az + (long)(n0 + rA1) * a_rstride + kbase + gA1 * 8;
    const ushort_t* bp0 = Wp + (long)(obase + rA0) * K + gA0 * 8;
    const ushort_t* bp1 = Wp + (long)(obase + rA1) * K + gA1 * 8;
    const int la0 = (w * 32) * 32, la1 = (w * 32 + 16) * 32;

    const int wr = (w >> 1) * 64, wc = (w & 1) * 64;
    const int fr = l & 15, ks = l >> 4;
    const int rsw = (ks ^ ((fr >> 1) & 3)) << 3;

    f32x4 acc[4][4];
#pragma unroll
    for (int m = 0; m < 4; ++m)
#pragma unroll
        for (int nf = 0; nf < 4; ++nf) acc[m][nf] = f32x4{0.f, 0.f, 0.f, 0.f};

    KLOOP(K);

    float dsum[4][4];
    if (DEN) {
#pragma unroll
        for (int m = 0; m < 4; ++m)
#pragma unroll
            for (int j2 = 0; j2 < 4; ++j2) dsum[m][j2] = 0.f;
    }
    float qsum[4];
    if (QGS) {
#pragma unroll
        for (int nf = 0; nf < 4; ++nf) qsum[nf] = 0.f;
    }

#pragma unroll
    for (int m = 0; m < 4; ++m) {
#pragma unroll
        for (int nf = 0; nf < 4; ++nf) {
            const int oo = o0 + wc + nf * 16 + fr;
            float bval = 0.f;
            if (EPI == EPI_RELU_BIAS || EPI == EPI_RES_BIAS) bval = bias[oo];
            float kw = 0.f;
            if (DEN) kw = bias[((z & 3) << 9) + oo];
#pragma unroll
            for (int j2 = 0; j2 < 4; ++j2) {
                const int nn = n0 + wr + m * 16 + ks * 4 + j2;
                const long ridx = (long)nn * O + oo;
                float v = acc[m][nf][j2];
                if (EPI == EPI_PHI)            v = fmaxf(v, 0.f) + 1.f;
                else if (EPI == EPI_RELU_BIAS) v = fmaxf(v + bval, 0.f);
                else if (EPI == EPI_RES_BIAS)  v = v + bval + b2f(auxb[(long)z * auxb_zstride + ridx]);
                else if (EPI == EPI_PRE)       v = b2f(auxb[(long)z * auxb_zstride + ridx]) + auxf[ridx] * v;
                if (DEN) dsum[m][j2] += v * kw;
                if (QGS) qsum[nf] += v;
                if (OBF) ((ushort_t*)OUTV)[(long)z * o_zstride + ridx] = f2b(v);
                else     ((float*)OUTV)[(long)z * o_zstride + ridx] = v;
            }
        }
    }

    if (DEN) {
#pragma unroll
        for (int m = 0; m < 4; ++m)
#pragma unroll
            for (int j2 = 0; j2 < 4; ++j2) {
                float d = dsum[m][j2];
                d += __shfl_xor(d, 1); d += __shfl_xor(d, 2);
                d += __shfl_xor(d, 4); d += __shfl_xor(d, 8);
                if (fr == 0) {
                    const int nn = n0 + wr + m * 16 + ks * 4 + j2;
                    atomicAdd((float*)&auxf[(long)z * N_DIM + nn], d);
                }
            }
    }
    if (QGS) {
#pragma unroll
        for (int nf = 0; nf < 4; ++nf) {
            float d = qsum[nf];
            d += __shfl_xor(d, 16);
            d += __shfl_xor(d, 32);
            if (ks == 0) {
                const int oo = o0 + wc + nf * 16 + fr;
                atomicAdd((float*)&auxf[((long)z << 9) + oo], d);
            }
        }
    }
}

// ---------------------------------------------------------------------------
// kv: kvp[nch][b][d][c] = sum_{n in 512-chunk nch} v0c[b][d][n] * khat[b][c][n]
// ---------------------------------------------------------------------------
__global__ __launch_bounds__(256, 3) void kv_mfma(
    const ushort_t* __restrict__ v0c, const ushort_t* __restrict__ khat,
    float* __restrict__ kvp)
{
    __shared__ ushort_t Als[2][128 * 32];
    __shared__ ushort_t Bls[2][128 * 32];
    const int tid = threadIdx.x;
    const int L = blockIdx.x;
    const int gpx = (gridDim.x >> 3) >> 2;
    const int xcd = L & 7;
    const int j = L >> 3;
    const int xtile = j & 3;
    const int g = xcd * gpx + (j >> 2);
    const int ytile = g & 3;
    const int z = g >> 2;
    const int c0 = xtile * 128, d0 = ytile * 128;
    const int b = z >> 3, nch = z & 7;

    const int w = tid >> 6, l = tid & 63;
    const int lr = l >> 2, lg = l & 3;
    const int rA0 = w * 32 + lr, rA1 = w * 32 + 16 + lr;
    const int gA0 = lg ^ ((rA0 >> 1) & 3), gA1 = lg ^ ((rA1 >> 1) & 3);
    const ushort_t* Ab = v0c + (long)b * CN_ + nch * 512;
    const ushort_t* Bb = khat + (long)b * CN_ + nch * 512;
    const ushort_t* ap0 = Ab + (long)(d0 + rA0) * N_DIM + gA0 * 8;
    const ushort_t* ap1 = Ab + (long)(d0 + rA1) * N_DIM + gA1 * 8;
    const ushort_t* bp0 = Bb + (long)(c0 + rA0) * N_DIM + gA0 * 8;
    const ushort_t* bp1 = Bb + (long)(c0 + rA1) * N_DIM + gA1 * 8;
    const int la0 = (w * 32) * 32, la1 = (w * 32 + 16) * 32;

    const int wr = (w >> 1) * 64, wc = (w & 1) * 64;
    const int fr = l & 15, ks = l >> 4;
    const int rsw = (ks ^ ((fr >> 1) & 3)) << 3;

    f32x4 acc[4][4];
#pragma unroll
    for (int m = 0; m < 4; ++m)
#pragma unroll
        for (int nf = 0; nf < 4; ++nf) acc[m][nf] = f32x4{0.f, 0.f, 0.f, 0.f};

    KLOOP(512);

    float* KV = kvp + ((long)(nch * 4 + b)) * 262144;
#pragma unroll
    for (int m = 0; m < 4; ++m)
#pragma unroll
        for (int nf = 0; nf < 4; ++nf) {
            const int cc = c0 + wc + nf * 16 + fr;
#pragma unroll
            for (int j2 = 0; j2 < 4; ++j2) {
                const int dd = d0 + wr + m * 16 + ks * 4 + j2;
                KV[(long)dd * 512 + cc] = acc[m][nf][j2];
            }
        }
}

// kvT[i] = f2b( (1/sqrt(512)) * sum_nch kvp[nch][i] )
__global__ __launch_bounds__(256) void cvt_scale8(
    const float* __restrict__ kvp, ushort_t* __restrict__ out)
{
    const float s = 0.044194173824159216f;
    const long i = ((long)blockIdx.x * 256 + threadIdx.x) * 4;
    const int b = (int)(i >> 18);
    const long j = i & 262143;
    float4 a = make_float4(0.f, 0.f, 0.f, 0.f);
#pragma unroll
    for (int nch = 0; nch < 8; ++nch) {
        float4 v = *(const float4*)&kvp[((long)(nch * 4 + b)) * 262144 + j];
        a.x += v.x; a.y += v.y; a.z += v.z; a.w += v.w;
    }
    union { ushort_t sh[4]; uint2 u; } p;
    p.sh[0] = f2b(a.x * s); p.sh[1] = f2b(a.y * s);
    p.sh[2] = f2b(a.z * s); p.sh[3] = f2b(a.w * s);
    *(uint2*)&out[i] = p.u;
}

// ---------------------------------------------------------------------------
// fused Wphi + ybar, INTERLEAVED, counted vmcnt (8 loads/tile in flight)
// ---------------------------------------------------------------------------
__global__ __launch_bounds__(256, 2) void ybar_gemm(
    const ushort_t* __restrict__ q12, const ushort_t* __restrict__ kvT,
    const ushort_t* __restrict__ xT12, const ushort_t* __restrict__ Wphi_b,
    const float* __restrict__ den12, ushort_t* __restrict__ y12)
{
    __shared__ ushort_t Als[2][128 * 32];
    __shared__ ushort_t Bls[2][128 * 32];
    __shared__ ushort_t Cls[2][128 * 32];
    __shared__ ushort_t Dls[2][128 * 32];
    const int tid = threadIdx.x;
    const int L = blockIdx.x;
    const int gpx = (gridDim.x >> 3) >> 2;
    const int xcd = L & 7;
    const int j = L >> 3;
    const int xtile = j & 3;
    const int g = xcd * gpx + (j >> 2);
    const int ytile = g & 31;
    const int mm = g >> 5;
    const int o0 = xtile * 128, n0 = ytile * 128;

    const int w = tid >> 6, l = tid & 63;
    const int lr = l >> 2, lg = l & 3;
    const int rA0 = w * 32 + lr, rA1 = w * 32 + 16 + lr;
    const int gA0 = lg ^ ((rA0 >> 1) & 3), gA1 = lg ^ ((rA1 >> 1) & 3);
    const long aoff0 = (long)(n0 + rA0) * 512 + gA0 * 8;
    const long aoff1 = (long)(n0 + rA1) * 512 + gA1 * 8;
    const long boff0 = (long)(o0 + rA0) * 512 + gA0 * 8;
    const long boff1 = (long)(o0 + rA1) * 512 + gA1 * 8;
    const int la0 = (w * 32) * 32, la1 = (w * 32 + 16) * 32;

    const int wr = (w >> 1) * 64, wc = (w & 1) * 64;
    const int fr = l & 15, ks = l >> 4;
    const int rsw = (ks ^ ((fr >> 1) & 3)) << 3;

    const ushort_t* pa0 = xT12 + (long)mm * CN_ + aoff0;
    const ushort_t* pa1 = xT12 + (long)mm * CN_ + aoff1;
    const ushort_t* pb0 = Wphi_b + boff0;
    const ushort_t* pb1 = Wphi_b + boff1;
    const ushort_t* qa0 = q12 + (long)mm * CN_ + aoff0;
    const ushort_t* qa1 = q12 + (long)mm * CN_ + aoff1;
    const ushort_t* kb0 = kvT + (long)(mm & 3) * 262144 + boff0;
    const ushort_t* kb1 = kvT + (long)(mm & 3) * 262144 + boff1;

    f32x4 accP[4][4], accQ[4][4];
#pragma unroll
    for (int m = 0; m < 4; ++m)
#pragma unroll
        for (int nf = 0; nf < 4; ++nf) {
            accP[m][nf] = f32x4{0.f, 0.f, 0.f, 0.f};
            accQ[m][nf] = f32x4{0.f, 0.f, 0.f, 0.f};
        }

#define STAGE2(q, koff) { \
    GLOAD(pa0 + (koff), &Als[q][la0]); GLOAD(pa1 + (koff), &Als[q][la1]); \
    GLOAD(pb0 + (koff), &Bls[q][la0]); GLOAD(pb1 + (koff), &Bls[q][la1]); \
    GLOAD(qa0 + (koff), &Cls[q][la0]); GLOAD(qa1 + (koff), &Cls[q][la1]); \
    GLOAD(kb0 + (koff), &Dls[q][la0]); GLOAD(kb1 + (koff), &Dls[q][la1]); }

#define COMPUTE2(q) { \
    bf16x8 af[4], bfv[4], cf[4], df[4]; \
    _Pragma("unroll") for (int m_ = 0; m_ < 4; ++m_) { \
        af[m_] = *(const bf16x8*)&Als[q][(wr + m_ * 16 + fr) * 32 + rsw]; \
        cf[m_] = *(const bf16x8*)&Cls[q][(wr + m_ * 16 + fr) * 32 + rsw]; } \
    _Pragma("unroll") for (int nf_ = 0; nf_ < 4; ++nf_) { \
        bfv[nf_] = *(const bf16x8*)&Bls[q][(wc + nf_ * 16 + fr) * 32 + rsw]; \
        df[nf_] = *(const bf16x8*)&Dls[q][(wc + nf_ * 16 + fr) * 32 + rsw]; } \
    _Pragma("unroll") for (int m_ = 0; m_ < 4; ++m_) \
        _Pragma("unroll") for (int nf_ = 0; nf_ < 4; ++nf_) { \
            accP[m_][nf_] = __builtin_amdgcn_mfma_f32_16x16x32_bf16( \
                af[m_], bfv[nf_], accP[m_][nf_], 0, 0, 0); \
            accQ[m_][nf_] = __builtin_amdgcn_mfma_f32_16x16x32_bf16( \
                cf[m_], df[nf_], accQ[m_][nf_], 0, 0, 0); } }

    STAGE2(0, 0);
    STAGE2(1, 32);
    int s_ = 0;
    while (true) {
        if (s_ + 1 < 16) { WAITV8 } else { WAITV0 }
        SBAR;
        COMPUTE2(s_ & 1);
        SBAR;
        if (s_ + 2 < 16) STAGE2(s_ & 1, (s_ + 2) * 32);
        ++s_;
        if (s_ >= 16) break;
    }
#undef STAGE2
#undef COMPUTE2

    const float* D = den12 + (long)mm * N_DIM;
    ushort_t* Y = y12 + (long)mm * CN_;
#pragma unroll
    for (int m = 0; m < 4; ++m) {
        float zr[4];
#pragma unroll
        for (int j2 = 0; j2 < 4; ++j2)
            zr[j2] = 1.f / (D[n0 + wr + m * 16 + ks * 4 + j2] + 1e-6f);
#pragma unroll
        for (int nf = 0; nf < 4; ++nf) {
            const int oo = o0 + wc + nf * 16 + fr;
#pragma unroll
            for (int j2 = 0; j2 < 4; ++j2) {
                const int nn = n0 + wr + m * 16 + ks * 4 + j2;
                Y[(long)nn * 512 + oo] = f2b(accQ[m][nf][j2] * zr[j2] * accP[m][nf][j2]);
            }
        }
    }
}

// ybar stage B: ybar[i] = (1/12) sum_mm y12[mm][i]
__global__ __launch_bounds__(256) void ybar_reduce(
    const ushort_t* __restrict__ y12, float* __restrict__ ybar)
{
    const long i = ((long)blockIdx.x * 256 + threadIdx.x) * 8;
    float s[8] = {0.f, 0.f, 0.f, 0.f, 0.f, 0.f, 0.f, 0.f};
    for (int mm = 0; mm < 12; ++mm) {
        uint4 u = *(const uint4*)&y12[(long)mm * CN_ + i];
        const ushort_t* us = (const ushort_t*)&u;
#pragma unroll
        for (int j = 0; j < 8; ++j) s[j] += b2f(us[j]);
    }
#pragma unroll
    for (int j = 0; j < 8; ++j) s[j] *= (1.f / 12.f);
    *(float4*)&ybar[i] = make_float4(s[0], s[1], s[2], s[3]);
    *(float4*)&ybar[i + 4] = make_float4(s[4], s[5], s[6], s[7]);
}

// bf16 [z][4096][512] -> bf16 [z][512][4096]; ALPHA: out *= alpha[z][n],
// and ksum[z][c] += sum_n t[n][c]*alpha[n] (atomicAdd; pre-zeroed).
template<int ALPHA>
__global__ __launch_bounds__(256) void transpose_b2b(
    const ushort_t* __restrict__ in, ushort_t* __restrict__ out,
    const float* __restrict__ alpha, float* __restrict__ ksum)
{
    __shared__ ushort_t t[64][72];
    const int tid = threadIdx.x;
    const int n0 = blockIdx.x * 64, c0 = blockIdx.y * 64, z = blockIdx.z;
    const ushort_t* I = in + (long)z * CN_;
    ushort_t* O = out + (long)z * CN_;
    const int r = tid >> 2, s8 = (tid & 3) * 16;
    uint4 u0 = *(const uint4*)&I[(long)(n0 + r) * 512 + c0 + s8];
    uint4 u1 = *(const uint4*)&I[(long)(n0 + r) * 512 + c0 + s8 + 8];
    *(uint4*)&t[r][s8] = u0;
    *(uint4*)&t[r][s8 + 8] = u1;
    __syncthreads();
    union { ushort_t sh[16]; uint4 u[2]; } p;
#pragma unroll
    for (int i = 0; i < 16; ++i) {
        ushort_t v = t[s8 + i][r];
        if (ALPHA) v = f2b(b2f(v) * alpha[(long)z * N_DIM + n0 + s8 + i]);
        p.sh[i] = v;
    }
    uint4* dst = (uint4*)&O[(long)(c0 + r) * N_DIM + n0 + s8];
    dst[0] = p.u[0]; dst[1] = p.u[1];
    if (ALPHA) {
        const int c = tid & 63, q = tid >> 6;
        float s = 0.f;
#pragma unroll
        for (int i = 0; i < 16; ++i) {
            const int n = q * 16 + i;
            s += b2f(t[n][c]) * alpha[(long)z * N_DIM + n0 + n];
        }
        atomicAdd(&ksum[((long)z << 9) + c0 + c], s);
    }
}

// all-weights fp32 -> bf16 in one dispatch
__global__ __launch_bounds__(256) void cvt_all(
    const float* __restrict__ s0, ushort_t* __restrict__ d0,
    const float* __restrict__ s1, ushort_t* __restrict__ d1,
    const float* __restrict__ s2, ushort_t* __restrict__ d2,
    const float* __restrict__ s3, ushort_t* __restrict__ d3,
    const float* __restrict__ s4, ushort_t* __restrict__ d4,
    const float* __restrict__ s5, ushort_t* __restrict__ d5)
{
    long i = ((long)blockIdx.x * 256 + threadIdx.x) * 4;
    const float* s; ushort_t* d; long off;
    if (i < 65536)        { s = s0; d = d0; off = i; }
    else if (i < 131072)  { s = s1; d = d1; off = i - 65536; }
    else if (i < 393216)  { s = s2; d = d2; off = i - 131072; }
    else if (i < 655360)  { s = s3; d = d3; off = i - 393216; }
    else if (i < 1703936) { s = s4; d = d4; off = i - 655360; }
    else                  { s = s5; d = d5; off = i - 1703936; }
    float4 v = *(const float4*)&s[off];
    union { ushort_t sh[4]; uint2 u; } p;
    p.sh[0] = f2b(v.x); p.sh[1] = f2b(v.y); p.sh[2] = f2b(v.z); p.sh[3] = f2b(v.w);
    *(uint2*)&d[off] = p.u;
}

// transpose fp32 [z][rows][cols] -> bf16 [z][cols][rows].
// Read phase remapped for per-instruction wave-contiguity: lanes 0..15 cover
// one full 256B row segment (4 segments/wave/instr); passthrough identical.
// Write phase unchanged (proven).
template<int PASSZ>
__global__ __launch_bounds__(256) void transpose_f2b(
    const float* __restrict__ in, ushort_t* __restrict__ out,
    int rows, int cols, long in_z, long out_z, float* __restrict__ passout)
{
    __shared__ float t[64][65];
    const int tid = threadIdx.x;
    const int n0 = blockIdx.x * 64, c0 = blockIdx.y * 64;
    const int z = blockIdx.z;
    const float* I = in + (long)z * in_z;
    ushort_t* Ot = out + (long)z * out_z;
    const bool dopass = PASSZ && (z >= 4);
    float* P = passout + (long)z * in_z;
    const int rq = tid >> 4;            // 0..15: row sub-index within pass
    const int cc = (tid & 15) * 4;      // 0..60: col within 64-float segment
#pragma unroll
    for (int p = 0; p < 4; ++p) {
        const int rr = p * 16 + rq;     // 0..63
        const long goff = (long)(c0 + rr) * cols + n0 + cc;
        float4 v = *(const float4*)&I[goff];
        if (dopass) *(float4*)&P[goff] = v;
        t[rr][cc] = v.x; t[rr][cc + 1] = v.y;
        t[rr][cc + 2] = v.z; t[rr][cc + 3] = v.w;
    }
    __syncthreads();
    const int r = tid >> 2, s4 = (tid & 3) * 16;
    union { ushort_t s[16]; uint4 u[2]; } pk;
#pragma unroll
    for (int i = 0; i < 16; ++i) pk.s[i] = f2b(t[s4 + i][r]);
    uint4* dst = (uint4*)&Ot[(long)(n0 + r) * rows + c0 + s4];
    dst[0] = pk.u[0]; dst[1] = pk.u[1];
}

// out[z][n] = scale * sum_c X[z][n][c] * w[(z&3)][c]
__global__ __launch_bounds__(256) void dot_rows(
    const ushort_t* __restrict__ X, const float* __restrict__ w,
    float* __restrict__ out, float scale)
{
    const int tid = threadIdx.x;
    const int rn = tid >> 2, cs = (tid & 3) * 128;
    const int z = blockIdx.y;
    const int n = blockIdx.x * 64 + rn;
    const ushort_t* row = X + (long)z * CN_ + (long)n * C_DIM;
    const float* wz = w + (long)(z & 3) * C_DIM;
    float s = 0.f;
    for (int i = 0; i < 128; i += 8) {
        uint4 u = *(const uint4*)&row[cs + i];
        const ushort_t* us = (const ushort_t*)&u;
#pragma unroll
        for (int k2 = 0; k2 < 8; ++k2) s += b2f(us[k2]) * wz[cs + i + k2];
    }
    s += __shfl_xor(s, 1); s += __shfl_xor(s, 2);
    if ((tid & 3) == 0) out[(long)z * N_DIM + n] = s * scale;
}

// alpha[b,n] = softmax_n(logits[b,:]) * N
__global__ __launch_bounds__(256) void softmax_alpha(
    const float* __restrict__ logits, float* __restrict__ alpha)
{
    int b = blockIdx.x, tid = threadIdx.x;
    const float* L = logits + (long)b * N_DIM;
    float* A = alpha + (long)b * N_DIM;
    float lv[16];
    float mx = -3.4e38f;
#pragma unroll
    for (int i = 0; i < 4; i++) {
        float4 v = *(const float4*)&L[tid * 4 + i * 1024];
        lv[4 * i + 0] = v.x; lv[4 * i + 1] = v.y; lv[4 * i + 2] = v.z; lv[4 * i + 3] = v.w;
        mx = fmaxf(mx, fmaxf(fmaxf(v.x, v.y), fmaxf(v.z, v.w)));
    }
    __shared__ float red[8];
    float m = mx;
#pragma unroll
    for (int off = 32; off; off >>= 1) m = fmaxf(m, __shfl_down(m, off, 64));
    int wid = tid >> 6, lane = tid & 63;
    if (lane == 0) red[wid] = m;
    __syncthreads();
    m = fmaxf(fmaxf(red[0], red[1]), fmaxf(red[2], red[3]));
    float e[16], s = 0.f;
#pragma unroll
    for (int i = 0; i < 16; i++) { e[i] = expf(lv[i] - m); s += e[i]; }
#pragma unroll
    for (int off = 32; off; off >>= 1) s += __shfl_down(s, off, 64);
    if (lane == 0) red[4 + wid] = s;
    __syncthreads();
    float S = red[4] + red[5] + red[6] + red[7];
    float sc = 4096.f / S;
#pragma unroll
    for (int i = 0; i < 4; i++)
        *(float4*)&A[tid * 4 + i * 1024] =
            make_float4(e[4 * i] * sc, e[4 * i + 1] * sc, e[4 * i + 2] * sc, e[4 * i + 3] * sc);
}

// row LayerNorm over c (512) per (z,n); IBF: bf16 input; OBF: bf16 output
template<int RELU, int OBF, int IBF>
__global__ __launch_bounds__(256) void ln_row(
    const void* __restrict__ inv, const float* __restrict__ g,
    const float* __restrict__ bt, void* __restrict__ outv)
{
    const int tid = threadIdx.x;
    const int r = tid >> 3, cs = (tid & 7) * 64;
    const long base = (((long)blockIdx.y * N_DIM) + blockIdx.x * 32 + r) * C_DIM + cs;
    float vv[64];
    float s = 0.f, s2 = 0.f;
    if (IBF) {
        const ushort_t* I = (const ushort_t*)inv + base;
#pragma unroll
        for (int i = 0; i < 8; ++i) {
            uint4 u = *(const uint4*)&I[i * 8];
            const ushort_t* us = (const ushort_t*)&u;
#pragma unroll
            for (int jj = 0; jj < 8; ++jj) {
                float f = b2f(us[jj]); vv[i * 8 + jj] = f; s += f; s2 += f * f;
            }
        }
    } else {
        const float* I = (const float*)inv + base;
#pragma unroll
        for (int i = 0; i < 16; ++i) {
            float4 v = *(const float4*)&I[i * 4];
            vv[i * 4] = v.x; vv[i * 4 + 1] = v.y; vv[i * 4 + 2] = v.z; vv[i * 4 + 3] = v.w;
            s += v.x + v.y + v.z + v.w;
            s2 += v.x * v.x + v.y * v.y + v.z * v.z + v.w * v.w;
        }
    }
#pragma unroll
    for (int off = 1; off < 8; off <<= 1) { s += __shfl_xor(s, off); s2 += __shfl_xor(s2, off); }
    const float mean = s * (1.f / 512.f);
    const float var = s2 * (1.f / 512.f) - mean * mean;
    const float rs = rsqrtf(var + 1e-6f);
#pragma unroll
    for (int i = 0; i < 64; i += 4) {
        float o[4];
#pragma unroll
        for (int jj = 0; jj < 4; ++jj) {
            float ov = (vv[i + jj] - mean) * rs * g[cs + i + jj] + bt[cs + i + jj];
            if (RELU) ov = fmaxf(ov, 0.f);
            o[jj] = ov;
        }
        if (OBF) {
            union { ushort_t s4[4]; uint2 u; } p;
            p.s4[0] = f2b(o[0]); p.s4[1] = f2b(o[1]); p.s4[2] = f2b(o[2]); p.s4[3] = f2b(o[3]);
            *(uint2*)&((ushort_t*)outv)[base + i] = p.u;
        } else {
            *(float4*)&((float*)outv)[base + i] = make_float4(o[0], o[1], o[2], o[3]);
        }
    }
}

// fused LN2 + relu + transpose: in bf16 [z][n][c] -> out fp32 [z][c][n]
__global__ __launch_bounds__(256) void ln_tr(
    const ushort_t* __restrict__ in, const float* __restrict__ g,
    const float* __restrict__ bt, float* __restrict__ out)
{
    __shared__ float t[32][513];
    const int tid = threadIdx.x;
    const int r = tid >> 3;
    const int lc = (tid & 7) * 8;
    const int z = blockIdx.y;
    const long n = (long)blockIdx.x * 32 + r;
    const ushort_t* I = in + ((long)z * N_DIM + n) * C_DIM;
    float vv[64];
    float s = 0.f, s2 = 0.f;
#pragma unroll
    for (int i = 0; i < 8; ++i) {
        const int c = i * 64 + lc;
        uint4 u = *(const uint4*)&I[c];
        const ushort_t* us = (const ushort_t*)&u;
#pragma unroll
        for (int jj = 0; jj < 8; ++jj) {
            float f = b2f(us[jj]); vv[i * 8 + jj] = f; s += f; s2 += f * f;
        }
    }
#pragma unroll
    for (int off = 1; off < 8; off <<= 1) { s += __shfl_xor(s, off); s2 += __shfl_xor(s2, off); }
    const float mean = s * (1.f / 512.f);
    const float var = s2 * (1.f / 512.f) - mean * mean;
    const float rs = rsqrtf(var + 1e-6f);
#pragma unroll
    for (int i = 0; i < 8; ++i) {
        const int c = i * 64 + lc;
#pragma unroll
        for (int jj = 0; jj < 8; ++jj) {
            float o = (vv[i * 8 + jj] - mean) * rs * g[c + jj] + bt[c + jj];
            t[r][c + jj] = fmaxf(o, 0.f);
        }
    }
    __syncthreads();
    float* O = out + (long)z * CN_ + (long)blockIdx.x * 32;
    for (int c = tid; c < 512; c += 256) {
        float* dst = O + (long)c * N_DIM;
#pragma unroll
        for (int i = 0; i < 32; i += 4)
            *(float4*)&dst[i] = make_float4(t[i][c], t[i + 1][c], t[i + 2][c], t[i + 3][c]);
    }
}

extern "C" void kernel_launch(void* const* d_in, const int* in_sizes, int n_in,
                              void* d_out, int out_size, void* d_ws, size_t ws_size,
                              hipStream_t stream)
{
    const float* x     = (const float*)d_in[0];
    const float* Wq    = (const float*)d_in[1];
    const float* Wk    = (const float*)d_in[2];
    const float* Wv    = (const float*)d_in[3];
    const float* Wphi  = (const float*)d_in[4];
    const float* ln1_w = (const float*)d_in[5];
    const float* ln1_b = (const float*)d_in[6];
    const float* fc1_w = (const float*)d_in[7];
    const float* fc1_bias = (const float*)d_in[8];
    const float* fc2_w = (const float*)d_in[9];
    const float* fc2_bias = (const float*)d_in[10];
    const float* ln2_w = (const float*)d_in[11];
    const float* ln2_b = (const float*)d_in[12];
    float* out = (float*)d_out;

    float* ws = (float*)d_ws;
    const long CN = CN_;
    // region map (float units); lifetimes are stream-sequential:
    ushort_t* xTfirst = (ushort_t*)ws;                 // [0,2CN)  (tln later)
    ushort_t* tln     = (ushort_t*)ws;
    ushort_t* xT12 = (ushort_t*)(ws + 2 * CN);         // [2CN,8CN)
    ushort_t* hbuf4 = (ushort_t*)(ws + 2 * CN);        // stage3 reuse [2CN,6CN)
    ushort_t* q12   = (ushort_t*)(ws + 8 * CN);        // [8CN,14CN)
    ushort_t* y12   = (ushort_t*)(ws + 14 * CN);       // [14CN,20CN)
    ushort_t* k0b = (ushort_t*)(ws + 20 * CN);         // [20CN,22CN) stage1
    ushort_t* v0b = (ushort_t*)(ws + 22 * CN);         // [22CN,24CN) stage1
    ushort_t* pre_b = (ushort_t*)(ws + 20 * CN);       // stage3 reuse
    ushort_t* khat = (ushort_t*)(ws + 24 * CN);        // [24CN,26CN) stage1
    ushort_t* v0c  = (ushort_t*)(ws + 26 * CN);        // [26CN,28CN) stage1
    ushort_t* ubuf_b = (ushort_t*)(ws + 24 * CN);      // stage3 reuse
    float* ybar = ws + 32 * CN;                        // [32CN,33CN)
    float* kvp  = ws + 33 * CN;                        // 8388608 floats
    ushort_t* kvT = (ushort_t*)(ws + 33 * CN + 8388608);
    float* wb = ws + 33 * CN + 8388608 + 524288;
    ushort_t* Wk_b   = (ushort_t*)(wb);
    ushort_t* Wq_b   = (ushort_t*)(wb + 32768);
    ushort_t* Wv_b   = (ushort_t*)(wb + 65536);
    ushort_t* Wphi_b = (ushort_t*)(wb + 196608);
    ushort_t* fc1_b16 = (ushort_t*)(wb + 327680);
    ushort_t* fc2_b16 = (ushort_t*)(wb + 851968);
    float* Qg     = wb + 1376256;                      // 2048
    float* ksum   = wb + 1378304;                      // 2048
    float* logits = wb + 1380352;
    float* alpha  = wb + 1396736;
    float* den12  = wb + 1413120;                      // 49152

    dim3 blk(256);

    // all weights -> bf16; zero atomic accumulators
    cvt_all<<<2688, blk, 0, stream>>>(Wk, Wk_b, Wq, Wq_b, Wv, Wv_b,
                                      Wphi, Wphi_b, fc1_w, fc1_b16, fc2_w, fc2_b16);
    hipMemsetAsync(Qg, 0, 4096 * sizeof(float), stream);        // Qg + ksum
    hipMemsetAsync(den12, 0, 49152 * sizeof(float), stream);

    // all 16 batches transposed; z>=4 also writes raw x to out (passthrough)
    transpose_f2b<1><<<dim3(64, 8, 16), blk, 0, stream>>>(
        x, xTfirst, 512, 4096, CN, CN, out);

    // stage 1: k0 (+Qg fused), v0, logits, alpha, khat (+ksum fused), v0c, kv
    mfma_gemm<EPI_PHI, true, true, false, true><<<512, blk, 0, stream>>>(
        Wk_b, xTfirst, k0b, nullptr, nullptr, Qg, 128, 512, 512, CN, CN, 0, 4, 32);
    mfma_gemm<EPI_NONE, false, true, false, false><<<512, blk, 0, stream>>>(
        Wv_b, xTfirst, v0b, nullptr, nullptr, nullptr, 512, 512, 512, CN, CN, 0, 4, 32);
    dot_rows<<<dim3(64, 4), blk, 0, stream>>>(k0b, Qg, logits, 1.f / 4096.f);
    softmax_alpha<<<4, blk, 0, stream>>>(logits, alpha);
    transpose_b2b<1><<<dim3(64, 8, 4), blk, 0, stream>>>(k0b, khat, alpha, ksum);
    transpose_b2b<0><<<dim3(64, 8, 4), blk, 0, stream>>>(v0b, v0c, nullptr, nullptr);
    kv_mfma<<<512, blk, 0, stream>>>(v0c, khat, kvp);
    cvt_scale8<<<1024, blk, 0, stream>>>(kvp, kvT);

    // stage 2: q (with fused den), interleaved phi+ybar, reduce
    mfma_gemm<EPI_PHI, true, true, true, false><<<1536, blk, 0, stream>>>(
        Wq_b, xT12, q12, ksum, nullptr, den12, 128, 512, 512, CN, CN, 0, 4, 32);
    ybar_gemm<<<1536, blk, 0, stream>>>(q12, kvT, xT12, Wphi_b, den12, y12);
    ybar_reduce<<<1024, blk, 0, stream>>>(y12, ybar);

    // stage 3: pre(bf16) = firstT + ybar*phiF; LN1; MLP; fused LN2+relu+transpose
    mfma_gemm<EPI_PRE, false, true, false, false><<<512, blk, 0, stream>>>(
        Wphi_b, xTfirst, pre_b, nullptr, xTfirst, ybar, 512, 512, 512, CN, CN, CN, 4, 32);
    ln_row<0, 1, 1><<<dim3(128, 4), blk, 0, stream>>>(pre_b, ln1_w, ln1_b, tln);
    mfma_gemm<EPI_RELU_BIAS, false, true, false, false><<<2048, blk, 0, stream>>>(
        fc1_b16, tln, hbuf4, fc1_bias, nullptr, nullptr,
        512, 2048, 512, CN, 8388608, 0, 16, 32);
    mfma_gemm<EPI_RES_BIAS, false, true, false, false><<<512, blk, 0, stream>>>(
        fc2_b16, hbuf4, ubuf_b, fc2_bias, tln, nullptr,
        2048, 512, 2048, 8388608, CN, CN, 4, 32);
    ln_tr<<<dim3(128, 4), blk, 0, stream>>>(ubuf_b, ln2_w, ln2_b, out);
}